// Round 1
// baseline (2499.199 us; speedup 1.0000x reference)
//
#include <hip/hip_runtime.h>
#include <math.h>

// Problem constants (match reference)
#define DM   1024   // d_model
#define DI   2048   // d_inner
#define NS   16     // d_state
#define RK   64     // dt_rank
#define LQ   2048   // seq len
#define NB   2      // batch
#define XD   96     // dt_rank + 2*d_state

// =====================================================================
// Generic fp32 GEMM:  C[M][N] = A[M][K] * W[N][K]^T   (both K-contiguous)
// 256 threads, per-thread TMxTN microtile, k-major LDS (+4 pad).
// EPI==1: fused bias + softplus epilogue (for dt_proj).
// =====================================================================
template<int BM, int BN, int BK, int TM, int TN, int EPI>
__global__ __launch_bounds__(256) void gemm_tt(
    const float* __restrict__ A, const float* __restrict__ W,
    float* __restrict__ C, const float* __restrict__ bias,
    int K, int lda, int ldw, int ldc)
{
    constexpr int NT = (BM / TM) * (BN / TN);
    static_assert(NT == 256, "block must be 256 threads");
    __shared__ float As[BK][BM + 4];
    __shared__ float Ws[BK][BN + 4];

    const int bm = blockIdx.y * BM;
    const int bn = blockIdx.x * BN;
    const int tx = threadIdx.x % (BN / TN);
    const int ty = threadIdx.x / (BN / TN);

    float acc[TM][TN];
#pragma unroll
    for (int i = 0; i < TM; ++i)
#pragma unroll
        for (int j = 0; j < TN; ++j) acc[i][j] = 0.f;

    for (int k0 = 0; k0 < K; k0 += BK) {
        // ---- stage A tile [BM][BK] -> As[BK][BM] (transposed, padded) ----
        {
            constexpr int NV = BM * BK / 4;        // float4 count
#pragma unroll
            for (int u = 0; u < (NV + NT - 1) / NT; ++u) {
                int v = u * NT + (int)threadIdx.x;
                if ((NV % NT == 0) || v < NV) {
                    int r  = v / (BK / 4);
                    int jc = (v % (BK / 4)) * 4;
                    float4 val = *(const float4*)(A + (size_t)(bm + r) * lda + k0 + jc);
                    As[jc + 0][r] = val.x; As[jc + 1][r] = val.y;
                    As[jc + 2][r] = val.z; As[jc + 3][r] = val.w;
                }
            }
        }
        // ---- stage W tile [BN][BK] -> Ws[BK][BN] ----
        {
            constexpr int NV = BN * BK / 4;
#pragma unroll
            for (int u = 0; u < (NV + NT - 1) / NT; ++u) {
                int v = u * NT + (int)threadIdx.x;
                if ((NV % NT == 0) || v < NV) {
                    int r  = v / (BK / 4);
                    int jc = (v % (BK / 4)) * 4;
                    float4 val = *(const float4*)(W + (size_t)(bn + r) * ldw + k0 + jc);
                    Ws[jc + 0][r] = val.x; Ws[jc + 1][r] = val.y;
                    Ws[jc + 2][r] = val.z; Ws[jc + 3][r] = val.w;
                }
            }
        }
        __syncthreads();

#pragma unroll
        for (int kk = 0; kk < BK; ++kk) {
            float a[TM], b[TN];
#pragma unroll
            for (int i = 0; i < TM; ++i) a[i] = As[kk][ty * TM + i];
#pragma unroll
            for (int j = 0; j < TN; ++j) b[j] = Ws[kk][tx * TN + j];
#pragma unroll
            for (int i = 0; i < TM; ++i)
#pragma unroll
                for (int j = 0; j < TN; ++j)
                    acc[i][j] = fmaf(a[i], b[j], acc[i][j]);
        }
        __syncthreads();
    }

    // ---- epilogue ----
#pragma unroll
    for (int i = 0; i < TM; ++i) {
        int row = bm + ty * TM + i;
#pragma unroll
        for (int j = 0; j < TN; ++j) {
            int col = bn + tx * TN + j;
            float v = acc[i][j];
            if (EPI == 1) {                 // bias + softplus (dt path)
                v += bias[col];
                v = (v > 20.f) ? v : log1pf(__expf(v));
            }
            C[(size_t)row * ldc + col] = v;
        }
    }
}

// =====================================================================
// Depthwise causal conv (k=4) + bias + silu.  Reads xi half of xz.
// =====================================================================
__global__ __launch_bounds__(256) void conv_silu(
    const float* __restrict__ xz, const float* __restrict__ cw,
    const float* __restrict__ cb, float* __restrict__ xi)
{
    int idx = blockIdx.x * 256 + threadIdx.x;      // over NB*LQ*DI
    int d = idx & (DI - 1);
    int l = (idx >> 11) & (LQ - 1);                // DI = 2^11
    int b = idx >> 22;                             // LQ*DI = 2^22
    const float* xcol = xz + (size_t)b * LQ * (2 * DI) + d;
    float acc = cb[d];
#pragma unroll
    for (int k = 0; k < 4; ++k) {
        int ls = l - 3 + k;
        if (ls >= 0) acc = fmaf(xcol[(size_t)ls * (2 * DI)], cw[d * 4 + k], acc);
    }
    xi[idx] = acc / (1.f + __expf(-acc));          // silu
}

// =====================================================================
// SSM scan. One lane per (b, d, n): h recurrence in a register,
// 16-lane shfl_xor reduce for y = sum_n h*C.  Fuses skip (D*xi) and
// silu(z) gate; writes y IN PLACE over xi (same element, read-before-
// write within the wave's instruction stream -> safe).
// =====================================================================
__global__ __launch_bounds__(256) void ssm_scan(
    const float* __restrict__ dt, const float* __restrict__ xdbl,
    float* xiy /* xi in, y out, aliased */, const float* xz,
    const float* __restrict__ A_log, const float* __restrict__ Dp)
{
    int t = blockIdx.x * 256 + threadIdx.x;        // NB*DI*NS = 65536
    int b = t >> 15;                               // DI*NS = 32768
    int d = (t >> 4) & (DI - 1);
    int n = t & 15;

    float Aa = -__expf(A_log[d * NS + n]);         // A = -exp(A_log)
    float Dd = Dp[d];
    float h  = 0.f;

    const float* dt_p = dt   + (size_t)b * LQ * DI + d;
    const float* bc_p = xdbl + (size_t)b * LQ * XD + RK + n;   // B then C
    const float* z_p  = xz   + (size_t)b * LQ * (2 * DI) + DI + d;
    float*       xy_p = xiy  + (size_t)b * LQ * DI + d;

    for (int l = 0; l < LQ; ++l) {
        float dtv = dt_p[0];
        float xv  = xy_p[0];
        float Bv  = bc_p[0];
        float Cv  = bc_p[NS];
        h = fmaf(h, __expf(dtv * Aa), dtv * xv * Bv);
        float yv = h * Cv;
        yv += __shfl_xor(yv, 1);
        yv += __shfl_xor(yv, 2);
        yv += __shfl_xor(yv, 4);
        yv += __shfl_xor(yv, 8);
        if (n == 0) {
            float zv = z_p[0];
            float sz = zv / (1.f + __expf(-zv));   // silu(z)
            xy_p[0] = (yv + xv * Dd) * sz;         // skip + gate
        }
        dt_p += DI; bc_p += XD; z_p += 2 * DI; xy_p += DI;
    }
}

// =====================================================================
// out = x + LayerNorm(m).  One 256-thread block per row (1024 cols).
// =====================================================================
__global__ __launch_bounds__(256) void ln_res(
    const float* __restrict__ x, const float* __restrict__ m,
    const float* __restrict__ w, const float* __restrict__ bb,
    float* __restrict__ out)
{
    int row = blockIdx.x;
    const float* mr = m + (size_t)row * DM;
    const float* xr = x + (size_t)row * DM;
    float*       op = out + (size_t)row * DM;

    float4 v = ((const float4*)mr)[threadIdx.x];
    float s = v.x + v.y + v.z + v.w;
    float q = v.x * v.x + v.y * v.y + v.z * v.z + v.w * v.w;
#pragma unroll
    for (int o = 32; o; o >>= 1) { s += __shfl_down(s, o); q += __shfl_down(q, o); }

    __shared__ float sred[4], qred[4];
    int wid = threadIdx.x >> 6, lane = threadIdx.x & 63;
    if (lane == 0) { sred[wid] = s; qred[wid] = q; }
    __syncthreads();
    s = sred[0] + sred[1] + sred[2] + sred[3];
    q = qred[0] + qred[1] + qred[2] + qred[3];

    float mu  = s * (1.f / DM);
    float var = q * (1.f / DM) - mu * mu;
    float rs  = rsqrtf(var + 1e-6f);

    float4 xv = ((const float4*)xr)[threadIdx.x];
    float4 wv = ((const float4*)w)[threadIdx.x];
    float4 bv = ((const float4*)bb)[threadIdx.x];
    float4 o;
    o.x = xv.x + (v.x - mu) * rs * wv.x + bv.x;
    o.y = xv.y + (v.y - mu) * rs * wv.y + bv.y;
    o.z = xv.z + (v.z - mu) * rs * wv.z + bv.z;
    o.w = xv.w + (v.w - mu) * rs * wv.w + bv.w;
    ((float4*)op)[threadIdx.x] = o;
}

// =====================================================================
extern "C" void kernel_launch(void* const* d_in, const int* in_sizes, int n_in,
                              void* d_out, int out_size, void* d_ws, size_t ws_size,
                              hipStream_t stream)
{
    const float* x        = (const float*)d_in[0];
    const float* in_w     = (const float*)d_in[1];   // [2*DI][DM]
    const float* conv_w   = (const float*)d_in[2];   // [DI][4]
    const float* conv_b   = (const float*)d_in[3];   // [DI]
    const float* xproj_w  = (const float*)d_in[4];   // [XD][DI]
    const float* dtproj_w = (const float*)d_in[5];   // [DI][RK]
    const float* dtproj_b = (const float*)d_in[6];   // [DI]
    const float* A_log    = (const float*)d_in[7];   // [DI][NS]
    const float* Dp       = (const float*)d_in[8];   // [DI]
    const float* out_w    = (const float*)d_in[9];   // [DM][DI]
    const float* ln_w     = (const float*)d_in[10];  // [DM]
    const float* ln_b     = (const float*)d_in[11];  // [DM]
    float* out = (float*)d_out;

    // Workspace layout (~136 MB). y is written in place over xi; the
    // mamba output m aliases the (dead-after-scan) xz buffer.
    char* ws = (char*)d_ws;
    float* xz   = (float*)ws;                               // [NB][LQ][2*DI]  67.1 MB
    float* xi   = (float*)(ws + (size_t)NB*LQ*2*DI*4);      // [NB][LQ][DI]    33.5 MB
    float* xdbl = (float*)(ws + (size_t)NB*LQ*3*DI*4);      // [NB][LQ][XD]     1.6 MB
    float* dtb  = (float*)(ws + (size_t)NB*LQ*3*DI*4 + (size_t)NB*LQ*XD*4); // 33.5 MB
    float* mb   = xz;                                       // alias: [NB][LQ][DM] 16.8 MB

    const int M = NB * LQ;  // 4096 token rows

    // 1. in_proj: xz = x @ in_w^T          (M x 4096, K=1024)
    gemm_tt<128,128,16,8,8,0><<<dim3((2*DI)/128, M/128), 256, 0, stream>>>(
        x, in_w, xz, nullptr, DM, DM, DM, 2*DI);

    // 2. depthwise causal conv + silu -> xi
    conv_silu<<<(NB*LQ*DI)/256, 256, 0, stream>>>(xz, conv_w, conv_b, xi);

    // 3. x_proj: xdbl = xi @ xproj_w^T     (M x 96, K=2048)
    gemm_tt<64,32,16,4,2,0><<<dim3(XD/32, M/64), 256, 0, stream>>>(
        xi, xproj_w, xdbl, nullptr, DI, DI, DI, XD);

    // 4. dt = softplus(xdbl[:, :RK] @ dtproj_w^T + b)   (M x 2048, K=64)
    gemm_tt<128,128,16,8,8,1><<<dim3(DI/128, M/128), 256, 0, stream>>>(
        xdbl, dtproj_w, dtb, dtproj_b, RK, XD, RK, DI);

    // 5. SSM scan (+ skip + gate), y over xi in place
    ssm_scan<<<(NB*DI*NS)/256, 256, 0, stream>>>(dtb, xdbl, xi, xz, A_log, Dp);

    // 6. out_proj: m = y @ out_w^T         (M x 1024, K=2048)
    gemm_tt<128,128,16,8,8,0><<<dim3(DM/128, M/128), 256, 0, stream>>>(
        xi, out_w, mb, nullptr, DI, DI, DI, DM);

    // 7. out = x + LayerNorm(m)
    ln_res<<<M, 256, 0, stream>>>(x, mb, ln_w, ln_b, out);
}

// Round 2
// 1043.922 us; speedup vs baseline: 2.3940x; 2.3940x over previous
//
#include <hip/hip_runtime.h>
#include <math.h>

// Problem constants (match reference)
#define DM   1024   // d_model
#define DI   2048   // d_inner
#define NS   16     // d_state
#define RK   64     // dt_rank
#define LQ   2048   // seq len
#define NB   2      // batch
#define XD   96     // dt_rank + 2*d_state
#define CCH  64     // scan chunks
#define CLEN 32     // LQ / CCH

#define UNPACK16(dst, ptr) do {                               \
    const float4* q_ = (const float4*)(ptr);                  \
    float4 q0=q_[0],q1=q_[1],q2=q_[2],q3=q_[3];               \
    dst[0]=q0.x; dst[1]=q0.y; dst[2]=q0.z; dst[3]=q0.w;       \
    dst[4]=q1.x; dst[5]=q1.y; dst[6]=q1.z; dst[7]=q1.w;       \
    dst[8]=q2.x; dst[9]=q2.y; dst[10]=q2.z; dst[11]=q2.w;     \
    dst[12]=q3.x; dst[13]=q3.y; dst[14]=q3.z; dst[15]=q3.w;   \
} while(0)

// =====================================================================
// Generic fp32 GEMM:  C[M][N] = A[M][K] * W[N][K]^T   (both K-contiguous)
// 256 threads, per-thread TMxTN microtile, k-major LDS (+4 pad).
// EPI==1: fused bias + softplus epilogue (for dt_proj).
// =====================================================================
template<int BM, int BN, int BK, int TM, int TN, int EPI>
__global__ __launch_bounds__(256) void gemm_tt(
    const float* __restrict__ A, const float* __restrict__ W,
    float* __restrict__ C, const float* __restrict__ bias,
    int K, int lda, int ldw, int ldc)
{
    constexpr int NT = (BM / TM) * (BN / TN);
    static_assert(NT == 256, "block must be 256 threads");
    __shared__ float As[BK][BM + 4];
    __shared__ float Ws[BK][BN + 4];

    const int bm = blockIdx.y * BM;
    const int bn = blockIdx.x * BN;
    const int tx = threadIdx.x % (BN / TN);
    const int ty = threadIdx.x / (BN / TN);

    float acc[TM][TN];
#pragma unroll
    for (int i = 0; i < TM; ++i)
#pragma unroll
        for (int j = 0; j < TN; ++j) acc[i][j] = 0.f;

    for (int k0 = 0; k0 < K; k0 += BK) {
        {
            constexpr int NV = BM * BK / 4;
#pragma unroll
            for (int u = 0; u < (NV + NT - 1) / NT; ++u) {
                int v = u * NT + (int)threadIdx.x;
                if ((NV % NT == 0) || v < NV) {
                    int r  = v / (BK / 4);
                    int jc = (v % (BK / 4)) * 4;
                    float4 val = *(const float4*)(A + (size_t)(bm + r) * lda + k0 + jc);
                    As[jc + 0][r] = val.x; As[jc + 1][r] = val.y;
                    As[jc + 2][r] = val.z; As[jc + 3][r] = val.w;
                }
            }
        }
        {
            constexpr int NV = BN * BK / 4;
#pragma unroll
            for (int u = 0; u < (NV + NT - 1) / NT; ++u) {
                int v = u * NT + (int)threadIdx.x;
                if ((NV % NT == 0) || v < NV) {
                    int r  = v / (BK / 4);
                    int jc = (v % (BK / 4)) * 4;
                    float4 val = *(const float4*)(W + (size_t)(bn + r) * ldw + k0 + jc);
                    Ws[jc + 0][r] = val.x; Ws[jc + 1][r] = val.y;
                    Ws[jc + 2][r] = val.z; Ws[jc + 3][r] = val.w;
                }
            }
        }
        __syncthreads();

#pragma unroll
        for (int kk = 0; kk < BK; ++kk) {
            float a[TM], b[TN];
#pragma unroll
            for (int i = 0; i < TM; ++i) a[i] = As[kk][ty * TM + i];
#pragma unroll
            for (int j = 0; j < TN; ++j) b[j] = Ws[kk][tx * TN + j];
#pragma unroll
            for (int i = 0; i < TM; ++i)
#pragma unroll
                for (int j = 0; j < TN; ++j)
                    acc[i][j] = fmaf(a[i], b[j], acc[i][j]);
        }
        __syncthreads();
    }

#pragma unroll
    for (int i = 0; i < TM; ++i) {
        int row = bm + ty * TM + i;
#pragma unroll
        for (int j = 0; j < TN; ++j) {
            int col = bn + tx * TN + j;
            float v = acc[i][j];
            if (EPI == 1) {
                v += bias[col];
                v = (v > 20.f) ? v : log1pf(__expf(v));
            }
            C[(size_t)row * ldc + col] = v;
        }
    }
}

// =====================================================================
// Depthwise causal conv (k=4) + bias + silu.  Reads xi half of xz.
// =====================================================================
__global__ __launch_bounds__(256) void conv_silu(
    const float* __restrict__ xz, const float* __restrict__ cw,
    const float* __restrict__ cb, float* __restrict__ xi)
{
    int idx = blockIdx.x * 256 + threadIdx.x;
    int d = idx & (DI - 1);
    int l = (idx >> 11) & (LQ - 1);
    int b = idx >> 22;
    const float* xcol = xz + (size_t)b * LQ * (2 * DI) + d;
    float acc = cb[d];
#pragma unroll
    for (int k = 0; k < 4; ++k) {
        int ls = l - 3 + k;
        if (ls >= 0) acc = fmaf(xcol[(size_t)ls * (2 * DI)], cw[d * 4 + k], acc);
    }
    xi[idx] = acc / (1.f + __expf(-acc));
}

// =====================================================================
// Chunked scan, phase A: per (b,d,chunk) local scan with h0=0.
// One lane owns a channel: 16 h-states + 16 cumulative a-products in
// registers. Emits summaries into the DEAD first half of the interleaved
// xz buffer (xi-preconv region, dead after conv_silu):
//   linear summary index s -> xz[(s>>11)*4096 + (s&2047)]
//   P (a-product) at s = ((b*CCH + c)*DI + d)*NS + n
//   h_end          at s + NB*CCH*DI*NS  (== byte offset +8388608 floats)
// Grid: NB*CCH*8 blocks of 256 threads (d = dg*256 + tid).
// =====================================================================
__global__ __launch_bounds__(256) void scan_phase_a(
    const float* __restrict__ dt, const float* __restrict__ xdbl,
    const float* __restrict__ xi, const float* __restrict__ A_log,
    float* __restrict__ sums)
{
    int blk = blockIdx.x;
    int dg  = blk & 7;
    int c   = (blk >> 3) & (CCH - 1);
    int b   = blk >> 9;
    int d   = dg * 256 + (int)threadIdx.x;
    int l0  = c * CLEN;

    float Aa[NS];
    {
        float tmp[NS];
        UNPACK16(tmp, A_log + d * NS);
#pragma unroll
        for (int n = 0; n < NS; ++n) Aa[n] = -__expf(tmp[n]);
    }
    float h[NS], P[NS];
#pragma unroll
    for (int n = 0; n < NS; ++n) { h[n] = 0.f; P[n] = 1.f; }

    const float* dtp = dt   + ((size_t)b * LQ + l0) * DI + d;
    const float* xp  = xi   + ((size_t)b * LQ + l0) * DI + d;
    const float* Bp  = xdbl + ((size_t)b * LQ + l0) * XD + RK;

    for (int l = 0; l < CLEN; ++l) {
        float dtv = dtp[0];
        float xv  = xp[0];
        float dtx = dtv * xv;
        float Bv[NS];
        UNPACK16(Bv, Bp);
#pragma unroll
        for (int n = 0; n < NS; ++n) {
            float a = __expf(dtv * Aa[n]);
            P[n] *= a;
            h[n] = fmaf(h[n], a, dtx * Bv[n]);
        }
        dtp += DI; xp += DI; Bp += XD;
    }

    size_t sbase = (((size_t)b * CCH + c) * DI + d) * NS;
    size_t off   = (sbase >> 11) * 4096 + (sbase & 2047);
    float4* Pd = (float4*)(sums + off);
    float4* Hd = (float4*)(sums + off + 8388608);
    Pd[0] = make_float4(P[0],  P[1],  P[2],  P[3]);
    Pd[1] = make_float4(P[4],  P[5],  P[6],  P[7]);
    Pd[2] = make_float4(P[8],  P[9],  P[10], P[11]);
    Pd[3] = make_float4(P[12], P[13], P[14], P[15]);
    Hd[0] = make_float4(h[0],  h[1],  h[2],  h[3]);
    Hd[1] = make_float4(h[4],  h[5],  h[6],  h[7]);
    Hd[2] = make_float4(h[8],  h[9],  h[10], h[11]);
    Hd[3] = make_float4(h[12], h[13], h[14], h[15]);
}

// =====================================================================
// Phase B: sequential over the 64 chunks; thread per (b,d,n).
// Overwrites the h_end slot with the chunk's TRUE initial state.
// =====================================================================
__global__ __launch_bounds__(256) void scan_phase_b(float* __restrict__ sums)
{
    int t = blockIdx.x * 256 + (int)threadIdx.x;    // 65536 = NB*DI*NS
    size_t s0  = ((size_t)(t >> 15) * CCH) * 32768 + (size_t)(t & 32767);
    size_t off = (s0 >> 11) * 4096 + (s0 & 2047);
    float H = 0.f;
#pragma unroll 8
    for (int c = 0; c < CCH; ++c) {
        float P  = sums[off];
        float he = sums[off + 8388608];
        sums[off + 8388608] = H;
        H = fmaf(P, H, he);
        off += 65536;                               // 16 rows of 4096
    }
}

// =====================================================================
// Phase C: re-scan each chunk from its true initial state; fuse
// y = sum_n h*C, skip (D*x), and silu(z) gate. y overwrites xi in place.
// =====================================================================
__global__ __launch_bounds__(256) void scan_phase_c(
    const float* __restrict__ dt, const float* __restrict__ xdbl,
    float* __restrict__ xiy, const float* __restrict__ xz,
    const float* __restrict__ A_log, const float* __restrict__ Dp,
    const float* __restrict__ sums)
{
    int blk = blockIdx.x;
    int dg  = blk & 7;
    int c   = (blk >> 3) & (CCH - 1);
    int b   = blk >> 9;
    int d   = dg * 256 + (int)threadIdx.x;
    int l0  = c * CLEN;

    float Aa[NS];
    {
        float tmp[NS];
        UNPACK16(tmp, A_log + d * NS);
#pragma unroll
        for (int n = 0; n < NS; ++n) Aa[n] = -__expf(tmp[n]);
    }
    float Dd = Dp[d];

    float h[NS];
    {
        size_t sbase = (((size_t)b * CCH + c) * DI + d) * NS;
        size_t off   = (sbase >> 11) * 4096 + (sbase & 2047);
        UNPACK16(h, sums + off + 8388608);          // true initial state
    }

    const float* dtp = dt   + ((size_t)b * LQ + l0) * DI + d;
    float*       xp  = xiy  + ((size_t)b * LQ + l0) * DI + d;
    const float* Bp  = xdbl + ((size_t)b * LQ + l0) * XD + RK;
    const float* zp  = xz   + ((size_t)b * LQ + l0) * (2 * DI) + DI + d;

    for (int l = 0; l < CLEN; ++l) {
        float dtv = dtp[0];
        float xv  = xp[0];
        float dtx = dtv * xv;
        float Bv[NS], Cv[NS];
        UNPACK16(Bv, Bp);
        UNPACK16(Cv, Bp + NS);
        float y0 = 0.f, y1 = 0.f, y2 = 0.f, y3 = 0.f;
#pragma unroll
        for (int n = 0; n < NS; n += 4) {
            float a0 = __expf(dtv * Aa[n+0]);
            float a1 = __expf(dtv * Aa[n+1]);
            float a2 = __expf(dtv * Aa[n+2]);
            float a3 = __expf(dtv * Aa[n+3]);
            h[n+0] = fmaf(h[n+0], a0, dtx * Bv[n+0]);
            h[n+1] = fmaf(h[n+1], a1, dtx * Bv[n+1]);
            h[n+2] = fmaf(h[n+2], a2, dtx * Bv[n+2]);
            h[n+3] = fmaf(h[n+3], a3, dtx * Bv[n+3]);
            y0 = fmaf(h[n+0], Cv[n+0], y0);
            y1 = fmaf(h[n+1], Cv[n+1], y1);
            y2 = fmaf(h[n+2], Cv[n+2], y2);
            y3 = fmaf(h[n+3], Cv[n+3], y3);
        }
        float yv = (y0 + y1) + (y2 + y3);
        float zv = zp[0];
        float sz = zv / (1.f + __expf(-zv));
        xp[0] = fmaf(xv, Dd, yv) * sz;
        dtp += DI; xp += DI; Bp += XD; zp += 2 * DI;
    }
}

// =====================================================================
// out = x + LayerNorm(m).  One 256-thread block per row (1024 cols).
// =====================================================================
__global__ __launch_bounds__(256) void ln_res(
    const float* __restrict__ x, const float* __restrict__ m,
    const float* __restrict__ w, const float* __restrict__ bb,
    float* __restrict__ out)
{
    int row = blockIdx.x;
    const float* mr = m + (size_t)row * DM;
    const float* xr = x + (size_t)row * DM;
    float*       op = out + (size_t)row * DM;

    float4 v = ((const float4*)mr)[threadIdx.x];
    float s = v.x + v.y + v.z + v.w;
    float q = v.x * v.x + v.y * v.y + v.z * v.z + v.w * v.w;
#pragma unroll
    for (int o = 32; o; o >>= 1) { s += __shfl_down(s, o); q += __shfl_down(q, o); }

    __shared__ float sred[4], qred[4];
    int wid = threadIdx.x >> 6, lane = threadIdx.x & 63;
    if (lane == 0) { sred[wid] = s; qred[wid] = q; }
    __syncthreads();
    s = sred[0] + sred[1] + sred[2] + sred[3];
    q = qred[0] + qred[1] + qred[2] + qred[3];

    float mu  = s * (1.f / DM);
    float var = q * (1.f / DM) - mu * mu;
    float rs  = rsqrtf(var + 1e-6f);

    float4 xv = ((const float4*)xr)[threadIdx.x];
    float4 wv = ((const float4*)w)[threadIdx.x];
    float4 bv = ((const float4*)bb)[threadIdx.x];
    float4 o;
    o.x = xv.x + (v.x - mu) * rs * wv.x + bv.x;
    o.y = xv.y + (v.y - mu) * rs * wv.y + bv.y;
    o.z = xv.z + (v.z - mu) * rs * wv.z + bv.z;
    o.w = xv.w + (v.w - mu) * rs * wv.w + bv.w;
    ((float4*)op)[threadIdx.x] = o;
}

// =====================================================================
extern "C" void kernel_launch(void* const* d_in, const int* in_sizes, int n_in,
                              void* d_out, int out_size, void* d_ws, size_t ws_size,
                              hipStream_t stream)
{
    const float* x        = (const float*)d_in[0];
    const float* in_w     = (const float*)d_in[1];
    const float* conv_w   = (const float*)d_in[2];
    const float* conv_b   = (const float*)d_in[3];
    const float* xproj_w  = (const float*)d_in[4];
    const float* dtproj_w = (const float*)d_in[5];
    const float* dtproj_b = (const float*)d_in[6];
    const float* A_log    = (const float*)d_in[7];
    const float* Dp       = (const float*)d_in[8];
    const float* out_w    = (const float*)d_in[9];
    const float* ln_w     = (const float*)d_in[10];
    const float* ln_b     = (const float*)d_in[11];
    float* out = (float*)d_out;

    // Workspace (~136 MB): xz | xi | xdbl | dtb.  Scan summaries live in
    // the dead (interleaved) first half of xz; mamba output aliases xz.
    char* ws = (char*)d_ws;
    float* xz   = (float*)ws;                               // [NB][LQ][2*DI]
    float* xi   = (float*)(ws + (size_t)NB*LQ*2*DI*4);      // [NB][LQ][DI]
    float* xdbl = (float*)(ws + (size_t)NB*LQ*3*DI*4);      // [NB][LQ][XD]
    float* dtb  = (float*)(ws + (size_t)NB*LQ*3*DI*4 + (size_t)NB*LQ*XD*4);
    float* mb   = xz;

    const int M = NB * LQ;

    // 1. in_proj
    gemm_tt<128,128,16,8,8,0><<<dim3((2*DI)/128, M/128), 256, 0, stream>>>(
        x, in_w, xz, nullptr, DM, DM, DM, 2*DI);

    // 2. conv + silu
    conv_silu<<<(NB*LQ*DI)/256, 256, 0, stream>>>(xz, conv_w, conv_b, xi);

    // 3. x_proj
    gemm_tt<64,32,16,4,2,0><<<dim3(XD/32, M/64), 256, 0, stream>>>(
        xi, xproj_w, xdbl, nullptr, DI, DI, DI, XD);

    // 4. dt_proj + softplus
    gemm_tt<128,128,16,8,8,1><<<dim3(DI/128, M/128), 256, 0, stream>>>(
        xdbl, dtproj_w, dtb, dtproj_b, RK, XD, RK, DI);

    // 5. chunked SSM scan (A: local scans, B: chunk-prefix fixup, C: rescan+fuse)
    scan_phase_a<<<NB*CCH*8, 256, 0, stream>>>(dtb, xdbl, xi, A_log, xz);
    scan_phase_b<<<(NB*DI*NS)/256, 256, 0, stream>>>(xz);
    scan_phase_c<<<NB*CCH*8, 256, 0, stream>>>(dtb, xdbl, xi, xz, A_log, Dp, xz);

    // 6. out_proj
    gemm_tt<128,128,16,8,8,0><<<dim3(DM/128, M/128), 256, 0, stream>>>(
        xi, out_w, mb, nullptr, DI, DI, DI, DM);

    // 7. out = x + LayerNorm(m)
    ln_res<<<M, 256, 0, stream>>>(x, mb, ln_w, ln_b, out);
}

// Round 5
// 676.176 us; speedup vs baseline: 3.6961x; 1.5439x over previous
//
#include <hip/hip_runtime.h>
#include <math.h>

// Problem constants (match reference)
#define DM   1024   // d_model
#define DI   2048   // d_inner
#define NS   16     // d_state
#define RK   64     // dt_rank
#define LQ   2048   // seq len
#define NB   2      // batch
#define XD   96     // dt_rank + 2*d_state
#define CCH  64     // scan chunks
#define CLEN 32     // LQ / CCH

typedef __attribute__((ext_vector_type(8))) short short8;
typedef __attribute__((ext_vector_type(4))) float f32x4;

#define UNPACK16(dst, ptr) do {                               \
    const float4* q_ = (const float4*)(ptr);                  \
    float4 q0=q_[0],q1=q_[1],q2=q_[2],q3=q_[3];               \
    dst[0]=q0.x; dst[1]=q0.y; dst[2]=q0.z; dst[3]=q0.w;       \
    dst[4]=q1.x; dst[5]=q1.y; dst[6]=q1.z; dst[7]=q1.w;       \
    dst[8]=q2.x; dst[9]=q2.y; dst[10]=q2.z; dst[11]=q2.w;     \
    dst[12]=q3.x; dst[13]=q3.y; dst[14]=q3.z; dst[15]=q3.w;   \
} while(0)

__device__ __forceinline__ unsigned short f2bf_rne(float f) {
    unsigned b = __float_as_uint(f);
    unsigned r = (b + 0x7fffu + ((b >> 16) & 1u)) >> 16;
    return (unsigned short)r;
}
__device__ __forceinline__ float bf2f(unsigned short u) {
    return __uint_as_float(((unsigned)u) << 16);
}

// =====================================================================
// split3: fp32 [R][K] -> bf16 [R][3K] blocked along K.
// AMODE=1 (A side):  [hi | hi | lo];  AMODE=0 (W side): [hi | lo | hi]
// so GEMM over 3K computes sum(ah*wh + ah*wl + al*wh)  (~fp32 accurate).
// grid: (K/1024, R), 256 threads, 4 elems/thread.
// =====================================================================
template<int AMODE>
__global__ __launch_bounds__(256) void split3(
    const float* __restrict__ s, unsigned short* __restrict__ d, int K)
{
    int c4 = blockIdx.x * 256 + threadIdx.x;     // over K/4
    int r  = blockIdx.y;
    float4 v = ((const float4*)(s + (size_t)r * K))[c4];
    unsigned short h0 = f2bf_rne(v.x), h1 = f2bf_rne(v.y),
                   h2 = f2bf_rne(v.z), h3 = f2bf_rne(v.w);
    unsigned short e0 = f2bf_rne(v.x - bf2f(h0)), e1 = f2bf_rne(v.y - bf2f(h1)),
                   e2 = f2bf_rne(v.z - bf2f(h2)), e3 = f2bf_rne(v.w - bf2f(h3));
    ushort4 hv = make_ushort4(h0, h1, h2, h3);
    ushort4 lv = make_ushort4(e0, e1, e2, e3);
    size_t base = (size_t)r * 3 * K;
    ((ushort4*)(d + base))[c4]         = hv;
    ((ushort4*)(d + base + K))[c4]     = AMODE ? hv : lv;
    ((ushort4*)(d + base + 2 * K))[c4] = AMODE ? lv : hv;
}

// =====================================================================
// bf16 MFMA GEMM (m97 structure):  C[M][N] f32 = A[M][K] * W[N][K]^T
// 128x128 tile, BK=64, 4 waves (2x2 of 64x64), 16x16x32 MFMA.
// global_load_lds(16B) direct staging, linear LDS dest + inverse-
// swizzled global source + XOR-swizzled ds_read (st-style, rule 21).
// =====================================================================
__device__ __forceinline__ void gl16(const unsigned short* g, unsigned short* l) {
    __builtin_amdgcn_global_load_lds(
        (const __attribute__((address_space(1))) unsigned int*)g,
        (__attribute__((address_space(3))) unsigned int*)l, 16, 0, 0);
}

__global__ __launch_bounds__(256) void gemm_mfma(
    const unsigned short* __restrict__ A, const unsigned short* __restrict__ W,
    float* __restrict__ C, int K, int ldc)
{
    __shared__ unsigned short Asm[128 * 64];   // [row][64] bf16, 128B rows
    __shared__ unsigned short Bsm[128 * 64];

    const int tid = threadIdx.x;
    const int l   = tid & 63;
    const int w   = tid >> 6;            // wave 0..3
    const int wr  = w >> 1, wc = w & 1;  // 2x2 wave grid (64x64 each)
    const int bm  = blockIdx.y * 128, bn = blockIdx.x * 128;

    f32x4 acc[4][4];
#pragma unroll
    for (int m = 0; m < 4; ++m)
#pragma unroll
        for (int n = 0; n < 4; ++n) acc[m][n] = (f32x4){0.f, 0.f, 0.f, 0.f};

    // Per-lane staging source: logical row = blockrow + w*32 + j*8 + l/8,
    // logical k-slot = (l%8) ^ (l/8)  (inverse of the read-side XOR).
    const int lr = l >> 3;                       // 0..7
    const int ls = (l & 7) ^ lr;                 // pre-swizzled slot
    const unsigned short* ga = A + (size_t)(bm + w * 32 + lr) * K + ls * 8;
    const unsigned short* gb = W + (size_t)(bn + w * 32 + lr) * K + ls * 8;

    // Fragment read offsets (bytes within a 128B row), XOR key (l&7)<<4:
    const int offk0 = ((l >> 4) * 16) ^ ((l & 7) << 4);
    const int offk1 = (64 + (l >> 4) * 16) ^ ((l & 7) << 4);
    const int arow  = (l & 15);

    const int nkt = K >> 6;
    for (int kt = 0; kt < nkt; ++kt) {
        const size_t kof = (size_t)kt * 64;
#pragma unroll
        for (int j = 0; j < 4; ++j) {
            gl16(ga + (size_t)j * 8 * K + kof, Asm + (w * 32 + j * 8) * 64);
            gl16(gb + (size_t)j * 8 * K + kof, Bsm + (w * 32 + j * 8) * 64);
        }
        __syncthreads();   // drains vmcnt -> staged data visible

#pragma unroll
        for (int kk = 0; kk < 2; ++kk) {
            const int offk = kk ? offk1 : offk0;
            short8 af[4], bf[4];
#pragma unroll
            for (int m = 0; m < 4; ++m)
                af[m] = *(const short8*)((const char*)Asm +
                         ((wr * 64 + m * 16 + arow) << 7) + offk);
#pragma unroll
            for (int n = 0; n < 4; ++n)
                bf[n] = *(const short8*)((const char*)Bsm +
                         ((wc * 64 + n * 16 + arow) << 7) + offk);
#pragma unroll
            for (int m = 0; m < 4; ++m)
#pragma unroll
                for (int n = 0; n < 4; ++n)
                    acc[m][n] = __builtin_amdgcn_mfma_f32_16x16x32_bf16(
                        af[m], bf[n], acc[m][n], 0, 0, 0);
        }
        __syncthreads();
    }

    // Epilogue: C[(l>>4)*4 + j][l&15] per 16x16 fragment (m89/m91 layout)
#pragma unroll
    for (int m = 0; m < 4; ++m) {
        int row = bm + wr * 64 + m * 16 + ((l >> 4) << 2);
#pragma unroll
        for (int n = 0; n < 4; ++n) {
            int col = bn + wc * 64 + n * 16 + (l & 15);
#pragma unroll
            for (int j = 0; j < 4; ++j)
                C[(size_t)(row + j) * ldc + col] = acc[m][n][j];
        }
    }
}

// =====================================================================
// fp32 GEMM (kept for the small/skinny x_proj and dt_proj)
// =====================================================================
template<int BM, int BN, int BK, int TM, int TN, int EPI>
__global__ __launch_bounds__(256) void gemm_tt(
    const float* __restrict__ A, const float* __restrict__ W,
    float* __restrict__ C, const float* __restrict__ bias,
    int K, int lda, int ldw, int ldc)
{
    constexpr int NT = (BM / TM) * (BN / TN);
    static_assert(NT == 256, "block must be 256 threads");
    __shared__ float As[BK][BM + 4];
    __shared__ float Ws[BK][BN + 4];

    const int bm = blockIdx.y * BM;
    const int bn = blockIdx.x * BN;
    const int tx = threadIdx.x % (BN / TN);
    const int ty = threadIdx.x / (BN / TN);

    float acc[TM][TN];
#pragma unroll
    for (int i = 0; i < TM; ++i)
#pragma unroll
        for (int j = 0; j < TN; ++j) acc[i][j] = 0.f;

    for (int k0 = 0; k0 < K; k0 += BK) {
        {
            constexpr int NV = BM * BK / 4;
#pragma unroll
            for (int u = 0; u < (NV + NT - 1) / NT; ++u) {
                int v = u * NT + (int)threadIdx.x;
                if ((NV % NT == 0) || v < NV) {
                    int r  = v / (BK / 4);
                    int jc = (v % (BK / 4)) * 4;
                    float4 val = *(const float4*)(A + (size_t)(bm + r) * lda + k0 + jc);
                    As[jc + 0][r] = val.x; As[jc + 1][r] = val.y;
                    As[jc + 2][r] = val.z; As[jc + 3][r] = val.w;
                }
            }
        }
        {
            constexpr int NV = BN * BK / 4;
#pragma unroll
            for (int u = 0; u < (NV + NT - 1) / NT; ++u) {
                int v = u * NT + (int)threadIdx.x;
                if ((NV % NT == 0) || v < NV) {
                    int r  = v / (BK / 4);
                    int jc = (v % (BK / 4)) * 4;
                    float4 val = *(const float4*)(W + (size_t)(bn + r) * ldw + k0 + jc);
                    Ws[jc + 0][r] = val.x; Ws[jc + 1][r] = val.y;
                    Ws[jc + 2][r] = val.z; Ws[jc + 3][r] = val.w;
                }
            }
        }
        __syncthreads();

#pragma unroll
        for (int kk = 0; kk < BK; ++kk) {
            float a[TM], b[TN];
#pragma unroll
            for (int i = 0; i < TM; ++i) a[i] = As[kk][ty * TM + i];
#pragma unroll
            for (int j = 0; j < TN; ++j) b[j] = Ws[kk][tx * TN + j];
#pragma unroll
            for (int i = 0; i < TM; ++i)
#pragma unroll
                for (int j = 0; j < TN; ++j)
                    acc[i][j] = fmaf(a[i], b[j], acc[i][j]);
        }
        __syncthreads();
    }

#pragma unroll
    for (int i = 0; i < TM; ++i) {
        int row = bm + ty * TM + i;
#pragma unroll
        for (int j = 0; j < TN; ++j) {
            int col = bn + tx * TN + j;
            float v = acc[i][j];
            if (EPI == 1) {
                v += bias[col];
                v = (v > 20.f) ? v : log1pf(__expf(v));
            }
            C[(size_t)row * ldc + col] = v;
        }
    }
}

// =====================================================================
// Depthwise causal conv (k=4) + bias + silu.
// =====================================================================
__global__ __launch_bounds__(256) void conv_silu(
    const float* __restrict__ xz, const float* __restrict__ cw,
    const float* __restrict__ cb, float* __restrict__ xi)
{
    int idx = blockIdx.x * 256 + threadIdx.x;
    int d = idx & (DI - 1);
    int l = (idx >> 11) & (LQ - 1);
    int b = idx >> 22;
    const float* xcol = xz + (size_t)b * LQ * (2 * DI) + d;
    float acc = cb[d];
#pragma unroll
    for (int k = 0; k < 4; ++k) {
        int ls = l - 3 + k;
        if (ls >= 0) acc = fmaf(xcol[(size_t)ls * (2 * DI)], cw[d * 4 + k], acc);
    }
    xi[idx] = acc / (1.f + __expf(-acc));
}

// =====================================================================
// Chunked scan, phases A/B/C (unchanged from R2, verified)
// =====================================================================
__global__ __launch_bounds__(256) void scan_phase_a(
    const float* __restrict__ dt, const float* __restrict__ xdbl,
    const float* __restrict__ xi, const float* __restrict__ A_log,
    float* __restrict__ sums)
{
    int blk = blockIdx.x;
    int dg  = blk & 7;
    int c   = (blk >> 3) & (CCH - 1);
    int b   = blk >> 9;
    int d   = dg * 256 + (int)threadIdx.x;
    int l0  = c * CLEN;

    float Aa[NS];
    {
        float tmp[NS];
        UNPACK16(tmp, A_log + d * NS);
#pragma unroll
        for (int n = 0; n < NS; ++n) Aa[n] = -__expf(tmp[n]);
    }
    float h[NS], P[NS];
#pragma unroll
    for (int n = 0; n < NS; ++n) { h[n] = 0.f; P[n] = 1.f; }

    const float* dtp = dt   + ((size_t)b * LQ + l0) * DI + d;
    const float* xp  = xi   + ((size_t)b * LQ + l0) * DI + d;
    const float* Bp  = xdbl + ((size_t)b * LQ + l0) * XD + RK;

    for (int l = 0; l < CLEN; ++l) {
        float dtv = dtp[0];
        float xv  = xp[0];
        float dtx = dtv * xv;
        float Bv[NS];
        UNPACK16(Bv, Bp);
#pragma unroll
        for (int n = 0; n < NS; ++n) {
            float a = __expf(dtv * Aa[n]);
            P[n] *= a;
            h[n] = fmaf(h[n], a, dtx * Bv[n]);
        }
        dtp += DI; xp += DI; Bp += XD;
    }

    size_t sbase = (((size_t)b * CCH + c) * DI + d) * NS;
    size_t off   = (sbase >> 11) * 4096 + (sbase & 2047);
    float4* Pd = (float4*)(sums + off);
    float4* Hd = (float4*)(sums + off + 8388608);
    Pd[0] = make_float4(P[0],  P[1],  P[2],  P[3]);
    Pd[1] = make_float4(P[4],  P[5],  P[6],  P[7]);
    Pd[2] = make_float4(P[8],  P[9],  P[10], P[11]);
    Pd[3] = make_float4(P[12], P[13], P[14], P[15]);
    Hd[0] = make_float4(h[0],  h[1],  h[2],  h[3]);
    Hd[1] = make_float4(h[4],  h[5],  h[6],  h[7]);
    Hd[2] = make_float4(h[8],  h[9],  h[10], h[11]);
    Hd[3] = make_float4(h[12], h[13], h[14], h[15]);
}

__global__ __launch_bounds__(256) void scan_phase_b(float* __restrict__ sums)
{
    int t = blockIdx.x * 256 + (int)threadIdx.x;
    size_t s0  = ((size_t)(t >> 15) * CCH) * 32768 + (size_t)(t & 32767);
    size_t off = (s0 >> 11) * 4096 + (s0 & 2047);
    float H = 0.f;
#pragma unroll 8
    for (int c = 0; c < CCH; ++c) {
        float P  = sums[off];
        float he = sums[off + 8388608];
        sums[off + 8388608] = H;
        H = fmaf(P, H, he);
        off += 65536;
    }
}

__global__ __launch_bounds__(256) void scan_phase_c(
    const float* __restrict__ dt, const float* __restrict__ xdbl,
    float* __restrict__ xiy, const float* __restrict__ xz,
    const float* __restrict__ A_log, const float* __restrict__ Dp,
    const float* __restrict__ sums)
{
    int blk = blockIdx.x;
    int dg  = blk & 7;
    int c   = (blk >> 3) & (CCH - 1);
    int b   = blk >> 9;
    int d   = dg * 256 + (int)threadIdx.x;
    int l0  = c * CLEN;

    float Aa[NS];
    {
        float tmp[NS];
        UNPACK16(tmp, A_log + d * NS);
#pragma unroll
        for (int n = 0; n < NS; ++n) Aa[n] = -__expf(tmp[n]);
    }
    float Dd = Dp[d];

    float h[NS];
    {
        size_t sbase = (((size_t)b * CCH + c) * DI + d) * NS;
        size_t off   = (sbase >> 11) * 4096 + (sbase & 2047);
        UNPACK16(h, sums + off + 8388608);
    }

    const float* dtp = dt   + ((size_t)b * LQ + l0) * DI + d;
    float*       xp  = xiy  + ((size_t)b * LQ + l0) * DI + d;
    const float* Bp  = xdbl + ((size_t)b * LQ + l0) * XD + RK;
    const float* zp  = xz   + ((size_t)b * LQ + l0) * (2 * DI) + DI + d;

    for (int l = 0; l < CLEN; ++l) {
        float dtv = dtp[0];
        float xv  = xp[0];
        float dtx = dtv * xv;
        float Bv[NS], Cv[NS];
        UNPACK16(Bv, Bp);
        UNPACK16(Cv, Bp + NS);
        float y0 = 0.f, y1 = 0.f, y2 = 0.f, y3 = 0.f;
#pragma unroll
        for (int n = 0; n < NS; n += 4) {
            float a0 = __expf(dtv * Aa[n+0]);
            float a1 = __expf(dtv * Aa[n+1]);
            float a2 = __expf(dtv * Aa[n+2]);
            float a3 = __expf(dtv * Aa[n+3]);
            h[n+0] = fmaf(h[n+0], a0, dtx * Bv[n+0]);
            h[n+1] = fmaf(h[n+1], a1, dtx * Bv[n+1]);
            h[n+2] = fmaf(h[n+2], a2, dtx * Bv[n+2]);
            h[n+3] = fmaf(h[n+3], a3, dtx * Bv[n+3]);
            y0 = fmaf(h[n+0], Cv[n+0], y0);
            y1 = fmaf(h[n+1], Cv[n+1], y1);
            y2 = fmaf(h[n+2], Cv[n+2], y2);
            y3 = fmaf(h[n+3], Cv[n+3], y3);
        }
        float yv = (y0 + y1) + (y2 + y3);
        float zv = zp[0];
        float sz = zv / (1.f + __expf(-zv));
        xp[0] = fmaf(xv, Dd, yv) * sz;
        dtp += DI; xp += DI; Bp += XD; zp += 2 * DI;
    }
}

// =====================================================================
// out = x + LayerNorm(m)
// =====================================================================
__global__ __launch_bounds__(256) void ln_res(
    const float* __restrict__ x, const float* __restrict__ m,
    const float* __restrict__ w, const float* __restrict__ bb,
    float* __restrict__ out)
{
    int row = blockIdx.x;
    const float* mr = m + (size_t)row * DM;
    const float* xr = x + (size_t)row * DM;
    float*       op = out + (size_t)row * DM;

    float4 v = ((const float4*)mr)[threadIdx.x];
    float s = v.x + v.y + v.z + v.w;
    float q = v.x * v.x + v.y * v.y + v.z * v.z + v.w * v.w;
#pragma unroll
    for (int o = 32; o; o >>= 1) { s += __shfl_down(s, o); q += __shfl_down(q, o); }

    __shared__ float sred[4], qred[4];
    int wid = threadIdx.x >> 6, lane = threadIdx.x & 63;
    if (lane == 0) { sred[wid] = s; qred[wid] = q; }
    __syncthreads();
    s = sred[0] + sred[1] + sred[2] + sred[3];
    q = qred[0] + qred[1] + qred[2] + qred[3];

    float mu  = s * (1.f / DM);
    float var = q * (1.f / DM) - mu * mu;
    float rs  = rsqrtf(var + 1e-6f);

    float4 xv = ((const float4*)xr)[threadIdx.x];
    float4 wv = ((const float4*)w)[threadIdx.x];
    float4 bv = ((const float4*)bb)[threadIdx.x];
    float4 o;
    o.x = xv.x + (v.x - mu) * rs * wv.x + bv.x;
    o.y = xv.y + (v.y - mu) * rs * wv.y + bv.y;
    o.z = xv.z + (v.z - mu) * rs * wv.z + bv.z;
    o.w = xv.w + (v.w - mu) * rs * wv.w + bv.w;
    ((float4*)op)[threadIdx.x] = o;
}

// =====================================================================
extern "C" void kernel_launch(void* const* d_in, const int* in_sizes, int n_in,
                              void* d_out, int out_size, void* d_ws, size_t ws_size,
                              hipStream_t stream)
{
    const float* x        = (const float*)d_in[0];
    const float* in_w     = (const float*)d_in[1];
    const float* conv_w   = (const float*)d_in[2];
    const float* conv_b   = (const float*)d_in[3];
    const float* xproj_w  = (const float*)d_in[4];
    const float* dtproj_w = (const float*)d_in[5];
    const float* dtproj_b = (const float*)d_in[6];
    const float* A_log    = (const float*)d_in[7];
    const float* Dp       = (const float*)d_in[8];
    const float* out_w    = (const float*)d_in[9];
    const float* ln_w     = (const float*)d_in[10];
    const float* ln_b     = (const float*)d_in[11];
    float* out = (float*)d_out;

    // Workspace (135.8 MB, same as R2). bf16 buffers overlay DEAD regions:
    //   Xe    @ xi region        (live only before conv writes xi)
    //   We_in @ xdbl/dtb region  (live only before x_proj/dt_proj write)
    //   Ye    @ xz+16MB          (written after scan C; mb uses xz[0:16MB))
    //   We_out@ dtb region       (dtb dead after scan C)
    char* ws = (char*)d_ws;
    float* xz   = (float*)ws;                               // 67,108,864 B
    float* xi   = (float*)(ws + 67108864);                  // 33,554,432 B
    float* xdbl = (float*)(ws + 100663296);                 //  1,572,864 B
    float* dtb  = (float*)(ws + 102236160);                 // 33,554,432 B
    float* mb   = xz;                                       // [4096][1024] f32

    unsigned short* Xe    = (unsigned short*)(ws + 67108864);   // 25.2 MB
    unsigned short* We_in = (unsigned short*)(ws + 100663296);  // 25.2 MB
    unsigned short* Ye    = (unsigned short*)(ws + 16777216);   // 50.3 MB
    unsigned short* We_o  = (unsigned short*)(ws + 102236160);  // 12.6 MB

    const int M = NB * LQ;  // 4096

    // 1. split x and in_w to bf16x3 (K=1024 -> 3072)
    split3<1><<<dim3(1, M),    256, 0, stream>>>(x,    Xe,    DM);
    split3<0><<<dim3(1, 2*DI), 256, 0, stream>>>(in_w, We_in, DM);

    // 2. in_proj on matrix cores: xz = Xe @ We_in^T  (K'=3072)
    gemm_mfma<<<dim3((2*DI)/128, M/128), 256, 0, stream>>>(
        Xe, We_in, xz, 3*DM, 2*DI);

    // 3. conv + silu (Xe dead now)
    conv_silu<<<(NB*LQ*DI)/256, 256, 0, stream>>>(xz, conv_w, conv_b, xi);

    // 4. x_proj (fp32, skinny N=96)   (We_in dead now)
    gemm_tt<64,32,16,4,2,0><<<dim3(XD/32, M/64), 256, 0, stream>>>(
        xi, xproj_w, xdbl, nullptr, DI, DI, DI, XD);

    // 5. dt_proj + softplus (fp32, K=64)
    gemm_tt<128,128,16,8,8,1><<<dim3(DI/128, M/128), 256, 0, stream>>>(
        xdbl, dtproj_w, dtb, dtproj_b, RK, XD, RK, DI);

    // 6. chunked SSM scan
    scan_phase_a<<<NB*CCH*8, 256, 0, stream>>>(dtb, xdbl, xi, A_log, xz);
    scan_phase_b<<<(NB*DI*NS)/256, 256, 0, stream>>>(xz);
    scan_phase_c<<<NB*CCH*8, 256, 0, stream>>>(dtb, xdbl, xi, xz, A_log, Dp, xz);

    // 7. split y and out_w to bf16x3 (K=2048 -> 6144); dtb/xdbl dead
    split3<1><<<dim3(2, M),  256, 0, stream>>>(xi,    Ye,   DI);
    split3<0><<<dim3(2, DM), 256, 0, stream>>>(out_w, We_o, DI);

    // 8. out_proj on matrix cores: mb = Ye @ We_o^T  (K'=6144)
    gemm_mfma<<<dim3(DM/128, M/128), 256, 0, stream>>>(
        Ye, We_o, mb, 3*DI, DM);

    // 9. out = x + LayerNorm(m)
    ln_res<<<M, 256, 0, stream>>>(x, mb, ln_w, ln_b, out);
}

// Round 7
// 561.816 us; speedup vs baseline: 4.4484x; 1.2036x over previous
//
#include <hip/hip_runtime.h>
#include <math.h>

// Problem constants (match reference)
#define DM   1024   // d_model
#define DI   2048   // d_inner
#define NS   16     // d_state
#define RK   64     // dt_rank
#define LQ   2048   // seq len
#define NB   2      // batch
#define XD   96     // dt_rank + 2*d_state
#define CCH  64     // scan chunks
#define CLEN 32     // LQ / CCH

typedef __attribute__((ext_vector_type(8))) short short8;
typedef __attribute__((ext_vector_type(4))) float f32x4;

#define UNPACK16(dst, ptr) do {                               \
    const float4* q_ = (const float4*)(ptr);                  \
    float4 q0=q_[0],q1=q_[1],q2=q_[2],q3=q_[3];               \
    dst[0]=q0.x; dst[1]=q0.y; dst[2]=q0.z; dst[3]=q0.w;       \
    dst[4]=q1.x; dst[5]=q1.y; dst[6]=q1.z; dst[7]=q1.w;       \
    dst[8]=q2.x; dst[9]=q2.y; dst[10]=q2.z; dst[11]=q2.w;     \
    dst[12]=q3.x; dst[13]=q3.y; dst[14]=q3.z; dst[15]=q3.w;   \
} while(0)

__device__ __forceinline__ unsigned short f2bf_rne(float f) {
    unsigned b = __float_as_uint(f);
    unsigned r = (b + 0x7fffu + ((b >> 16) & 1u)) >> 16;
    return (unsigned short)r;
}
__device__ __forceinline__ float bf2f(unsigned short u) {
    return __uint_as_float(((unsigned)u) << 16);
}

// =====================================================================
// split2: fp32 [R][K] -> bf16 hi[R][K] + lo[R][K]  (hi+lo ~= fp32).
// flat grid: R*K/1024 blocks, 4 cols/thread.
// =====================================================================
__global__ __launch_bounds__(256) void split2(
    const float* __restrict__ s, unsigned short* __restrict__ hi,
    unsigned short* __restrict__ lo, int K)
{
    int idx = blockIdx.x * 256 + threadIdx.x;
    int c4 = idx % (K / 4);
    int r  = idx / (K / 4);
    float4 v = ((const float4*)(s + (size_t)r * K))[c4];
    unsigned short h0 = f2bf_rne(v.x), h1 = f2bf_rne(v.y),
                   h2 = f2bf_rne(v.z), h3 = f2bf_rne(v.w);
    unsigned short e0 = f2bf_rne(v.x - bf2f(h0)), e1 = f2bf_rne(v.y - bf2f(h1)),
                   e2 = f2bf_rne(v.z - bf2f(h2)), e3 = f2bf_rne(v.w - bf2f(h3));
    ((ushort4*)(hi + (size_t)r * K))[c4] = make_ushort4(h0, h1, h2, h3);
    ((ushort4*)(lo + (size_t)r * K))[c4] = make_ushort4(e0, e1, e2, e3);
}

// x_proj weight, padded 96 -> 128 rows (pad rows = 0). grid (K/1024, 128).
__global__ __launch_bounds__(256) void split2_pad(
    const float* __restrict__ s, unsigned short* __restrict__ hi,
    unsigned short* __restrict__ lo, int K, int rValid)
{
    int c4 = blockIdx.x * 256 + threadIdx.x;
    int r  = blockIdx.y;
    float4 v = make_float4(0.f, 0.f, 0.f, 0.f);
    if (r < rValid) v = ((const float4*)(s + (size_t)r * K))[c4];
    unsigned short h0 = f2bf_rne(v.x), h1 = f2bf_rne(v.y),
                   h2 = f2bf_rne(v.z), h3 = f2bf_rne(v.w);
    unsigned short e0 = f2bf_rne(v.x - bf2f(h0)), e1 = f2bf_rne(v.y - bf2f(h1)),
                   e2 = f2bf_rne(v.z - bf2f(h2)), e3 = f2bf_rne(v.w - bf2f(h3));
    ((ushort4*)(hi + (size_t)r * K))[c4] = make_ushort4(h0, h1, h2, h3);
    ((ushort4*)(lo + (size_t)r * K))[c4] = make_ushort4(e0, e1, e2, e3);
}

// dt A-operand: xdbl[:, :64] (row stride XD=96) -> hi/lo [4096][64]. grid 1024.
__global__ __launch_bounds__(256) void split2_dtA(
    const float* __restrict__ xdbl, unsigned short* __restrict__ hi,
    unsigned short* __restrict__ lo)
{
    int idx = blockIdx.x * 256 + threadIdx.x;   // over 4096*64
    int r = idx >> 6, c = idx & 63;
    float v = xdbl[(size_t)r * XD + c];
    unsigned short h = f2bf_rne(v);
    unsigned short e = f2bf_rne(v - bf2f(h));
    hi[(size_t)r * 64 + c] = h;
    lo[(size_t)r * 64 + c] = e;
}

// =====================================================================
// bf16x3 MFMA GEMM on hi/lo pairs:  C = A * W^T  (~fp32 accurate).
// Logical K' = 3K; K-tile kt maps to block b=kt/(K/64):
//   A side: b<2 -> hi, b==2 -> lo     ([hi|hi|lo])
//   W side: b==1 -> lo, else hi       ([hi|lo|hi])
// 128x128 tile, BK=64, 4 waves (2x2 of 64x64), 16x16x32 MFMA,
// global_load_lds(16B), pre-swizzled source + XOR-swizzled ds_read.
// EPI: 0 plain C0[ldc]; 1 split x/z (in_proj); 2 split-K partials, col<96
//      (x_proj); 3 softplus+bias (dt_proj).
// =====================================================================
__device__ __forceinline__ void gl16(const unsigned short* g, unsigned short* l) {
    __builtin_amdgcn_global_load_lds(
        (const __attribute__((address_space(1))) unsigned int*)g,
        (__attribute__((address_space(3))) unsigned int*)l, 16, 0, 0);
}

template<int EPI>
__global__ __launch_bounds__(256) void gemm_mfma3(
    const unsigned short* __restrict__ Ahi, const unsigned short* __restrict__ Alo,
    const unsigned short* __restrict__ Whi, const unsigned short* __restrict__ Wlo,
    float* __restrict__ C0, float* __restrict__ C1,
    const float* __restrict__ bias, int K, int nkt_per, int ldc)
{
    __shared__ unsigned short Asm[128 * 64];   // [row][64] bf16, 128B rows
    __shared__ unsigned short Bsm[128 * 64];

    const int tid = threadIdx.x;
    const int l   = tid & 63;
    const int w   = tid >> 6;            // wave 0..3
    const int wr  = w >> 1, wc = w & 1;  // 2x2 wave grid (64x64 each)
    const int bm  = blockIdx.y * 128, bn = blockIdx.x * 128;
    const int ktpb = K >> 6;             // K-tiles per hi/lo block
    const int kt0  = blockIdx.z * nkt_per;

    f32x4 acc[4][4];
#pragma unroll
    for (int m = 0; m < 4; ++m)
#pragma unroll
        for (int n = 0; n < 4; ++n) acc[m][n] = (f32x4){0.f, 0.f, 0.f, 0.f};

    // Per-lane staging source: logical row = base + w*32 + j*8 + l/8,
    // logical k-slot = (l%8) ^ (l/8)  (inverse of the read-side XOR).
    const int lr = l >> 3;
    const int ls = (l & 7) ^ lr;
    const size_t roA = (size_t)(bm + w * 32 + lr) * K + ls * 8;
    const size_t roB = (size_t)(bn + w * 32 + lr) * K + ls * 8;

    const int offk0 = ((l >> 4) * 16) ^ ((l & 7) << 4);
    const int offk1 = (64 + (l >> 4) * 16) ^ ((l & 7) << 4);
    const int arow  = (l & 15);

    for (int i = 0; i < nkt_per; ++i) {
        const int kt  = kt0 + i;
        const int blk = kt / ktpb;
        const size_t kof = (size_t)(kt - blk * ktpb) * 64;
        const unsigned short* Ab = (blk < 2)  ? Ahi : Alo;
        const unsigned short* Wb = (blk == 1) ? Wlo : Whi;
#pragma unroll
        for (int j = 0; j < 4; ++j) {
            gl16(Ab + roA + (size_t)j * 8 * K + kof, Asm + (w * 32 + j * 8) * 64);
            gl16(Wb + roB + (size_t)j * 8 * K + kof, Bsm + (w * 32 + j * 8) * 64);
        }
        __syncthreads();   // drains vmcnt -> staged data visible

#pragma unroll
        for (int kk = 0; kk < 2; ++kk) {
            const int offk = kk ? offk1 : offk0;
            short8 af[4], bf[4];
#pragma unroll
            for (int m = 0; m < 4; ++m)
                af[m] = *(const short8*)((const char*)Asm +
                         ((wr * 64 + m * 16 + arow) << 7) + offk);
#pragma unroll
            for (int n = 0; n < 4; ++n)
                bf[n] = *(const short8*)((const char*)Bsm +
                         ((wc * 64 + n * 16 + arow) << 7) + offk);
#pragma unroll
            for (int m = 0; m < 4; ++m)
#pragma unroll
                for (int n = 0; n < 4; ++n)
                    acc[m][n] = __builtin_amdgcn_mfma_f32_16x16x32_bf16(
                        af[m], bf[n], acc[m][n], 0, 0, 0);
        }
        __syncthreads();
    }

    // Epilogue: C row=(l>>4)*4+j, col=l&15 per 16x16 fragment
#pragma unroll
    for (int m = 0; m < 4; ++m) {
        int row = bm + wr * 64 + m * 16 + ((l >> 4) << 2);
#pragma unroll
        for (int n = 0; n < 4; ++n) {
            int col = bn + wc * 64 + n * 16 + (l & 15);
#pragma unroll
            for (int j = 0; j < 4; ++j) {
                float v = acc[m][n][j];
                size_t r = (size_t)(row + j);
                if (EPI == 0) {
                    C0[r * ldc + col] = v;
                } else if (EPI == 1) {          // in_proj: split x | z
                    if (col < DI) C0[r * DI + col]        = v;
                    else          C1[r * DI + (col - DI)] = v;
                } else if (EPI == 2) {          // x_proj: split-K partials
                    if (col < XD)
                        C0[((size_t)blockIdx.z * (NB * LQ) + r) * XD + col] = v;
                } else {                        // dt_proj: softplus + bias
                    v += bias[col];
                    v = (v > 20.f) ? v : log1pf(__expf(v));
                    C0[r * DI + col] = v;
                }
            }
        }
    }
}

// reduce 8 split-K partials -> xdbl [4096][96]
__global__ __launch_bounds__(256) void reduce8(
    const float* __restrict__ part, float* __restrict__ xdbl)
{
    int idx = blockIdx.x * 256 + threadIdx.x;   // over 4096*96
    float s = 0.f;
#pragma unroll
    for (int k = 0; k < 8; ++k) s += part[(size_t)k * (NB * LQ) * XD + idx];
    xdbl[idx] = s;
}

// =====================================================================
// Depthwise causal conv (k=4) + bias + silu; emits bf16 hi/lo of result.
// bufX: [4096 tokens][2048] deinterleaved x-half of in_proj.
// =====================================================================
__global__ __launch_bounds__(256) void conv_silu2(
    const float* __restrict__ bx, const float* __restrict__ cw,
    const float* __restrict__ cb, unsigned short* __restrict__ xhi,
    unsigned short* __restrict__ xlo)
{
    int idx = blockIdx.x * 256 + threadIdx.x;      // over 4096*2048
    int d = idx & (DI - 1);
    int t = idx >> 11;                             // token
    int l = t & (LQ - 1);
    float acc = cb[d];
#pragma unroll
    for (int k = 0; k < 4; ++k) {
        int ls = l - 3 + k;
        if (ls >= 0) acc = fmaf(bx[(size_t)(t - 3 + k) * DI + d], cw[d * 4 + k], acc);
    }
    float y = acc / (1.f + __expf(-acc));          // silu
    unsigned short h = f2bf_rne(y);
    xhi[idx] = h;
    xlo[idx] = f2bf_rne(y - bf2f(h));
}

// =====================================================================
// Chunked scan. x is read as hi+lo (exact to ~2^-17).
// Phase A: per (b,d,chunk) local scan, h0=0 -> P (a-prod), Hs (h_end).
// =====================================================================
__global__ __launch_bounds__(256) void scan_phase_a(
    const float* __restrict__ dt, const float* __restrict__ xdbl,
    const unsigned short* __restrict__ xhi, const unsigned short* __restrict__ xlo,
    const float* __restrict__ A_log, float* __restrict__ P, float* __restrict__ Hs)
{
    int blk = blockIdx.x;
    int dg  = blk & 7;
    int c   = (blk >> 3) & (CCH - 1);
    int b   = blk >> 9;
    int d   = dg * 256 + (int)threadIdx.x;
    int l0  = c * CLEN;

    float Aa[NS];
    {
        float tmp[NS];
        UNPACK16(tmp, A_log + d * NS);
#pragma unroll
        for (int n = 0; n < NS; ++n) Aa[n] = -__expf(tmp[n]);
    }
    float h[NS], Pr[NS];
#pragma unroll
    for (int n = 0; n < NS; ++n) { h[n] = 0.f; Pr[n] = 1.f; }

    size_t base = ((size_t)b * LQ + l0) * DI + d;
    const float* dtp = dt + base;
    const unsigned short* xh = xhi + base;
    const unsigned short* xl = xlo + base;
    const float* Bp  = xdbl + ((size_t)b * LQ + l0) * XD + RK;

    for (int l = 0; l < CLEN; ++l) {
        float dtv = dtp[0];
        float xv  = bf2f(xh[0]) + bf2f(xl[0]);
        float dtx = dtv * xv;
        float Bv[NS];
        UNPACK16(Bv, Bp);
#pragma unroll
        for (int n = 0; n < NS; ++n) {
            float a = __expf(dtv * Aa[n]);
            Pr[n] *= a;
            h[n] = fmaf(h[n], a, dtx * Bv[n]);
        }
        dtp += DI; xh += DI; xl += DI; Bp += XD;
    }

    size_t off = (((size_t)b * CCH + c) * DI + d) * NS;
    float4* Pd = (float4*)(P + off);
    float4* Hd = (float4*)(Hs + off);
    Pd[0] = make_float4(Pr[0],  Pr[1],  Pr[2],  Pr[3]);
    Pd[1] = make_float4(Pr[4],  Pr[5],  Pr[6],  Pr[7]);
    Pd[2] = make_float4(Pr[8],  Pr[9],  Pr[10], Pr[11]);
    Pd[3] = make_float4(Pr[12], Pr[13], Pr[14], Pr[15]);
    Hd[0] = make_float4(h[0],  h[1],  h[2],  h[3]);
    Hd[1] = make_float4(h[4],  h[5],  h[6],  h[7]);
    Hd[2] = make_float4(h[8],  h[9],  h[10], h[11]);
    Hd[3] = make_float4(h[12], h[13], h[14], h[15]);
}

// Phase B: sequential over 64 chunks; Hs slot <- chunk's TRUE initial state.
__global__ __launch_bounds__(256) void scan_phase_b(
    const float* __restrict__ P, float* __restrict__ Hs)
{
    int t = blockIdx.x * 256 + (int)threadIdx.x;    // NB*DI*NS = 65536
    size_t off = ((size_t)(t >> 15) * CCH) * (DI * NS) + (size_t)(t & 32767);
    float H = 0.f;
#pragma unroll 8
    for (int c = 0; c < CCH; ++c) {
        float Pv = P[off];
        float he = Hs[off];
        Hs[off] = H;
        H = fmaf(Pv, H, he);
        off += DI * NS;
    }
}

// Phase C: re-scan from true initial state; fuse y, D-skip, silu(z) gate.
// Writes y as bf16 hi/lo IN PLACE over xhi/xlo (feeds out_proj directly).
__global__ __launch_bounds__(256) void scan_phase_c(
    const float* __restrict__ dt, const float* __restrict__ xdbl,
    unsigned short* xhi, unsigned short* xlo, const float* __restrict__ bz,
    const float* __restrict__ A_log, const float* __restrict__ Dp,
    const float* __restrict__ Hs)
{
    int blk = blockIdx.x;
    int dg  = blk & 7;
    int c   = (blk >> 3) & (CCH - 1);
    int b   = blk >> 9;
    int d   = dg * 256 + (int)threadIdx.x;
    int l0  = c * CLEN;

    float Aa[NS];
    {
        float tmp[NS];
        UNPACK16(tmp, A_log + d * NS);
#pragma unroll
        for (int n = 0; n < NS; ++n) Aa[n] = -__expf(tmp[n]);
    }
    float Dd = Dp[d];

    float h[NS];
    UNPACK16(h, Hs + (((size_t)b * CCH + c) * DI + d) * NS);

    size_t base = ((size_t)b * LQ + l0) * DI + d;
    const float* dtp = dt + base;
    unsigned short* xh = xhi + base;
    unsigned short* xl = xlo + base;
    const float* Bp  = xdbl + ((size_t)b * LQ + l0) * XD + RK;
    const float* zp  = bz + base;

    for (int l = 0; l < CLEN; ++l) {
        float dtv = dtp[0];
        float xv  = bf2f(xh[0]) + bf2f(xl[0]);
        float dtx = dtv * xv;
        float Bv[NS], Cv[NS];
        UNPACK16(Bv, Bp);
        UNPACK16(Cv, Bp + NS);
        float y0 = 0.f, y1 = 0.f, y2 = 0.f, y3 = 0.f;
#pragma unroll
        for (int n = 0; n < NS; n += 4) {
            float a0 = __expf(dtv * Aa[n+0]);
            float a1 = __expf(dtv * Aa[n+1]);
            float a2 = __expf(dtv * Aa[n+2]);
            float a3 = __expf(dtv * Aa[n+3]);
            h[n+0] = fmaf(h[n+0], a0, dtx * Bv[n+0]);
            h[n+1] = fmaf(h[n+1], a1, dtx * Bv[n+1]);
            h[n+2] = fmaf(h[n+2], a2, dtx * Bv[n+2]);
            h[n+3] = fmaf(h[n+3], a3, dtx * Bv[n+3]);
            y0 = fmaf(h[n+0], Cv[n+0], y0);
            y1 = fmaf(h[n+1], Cv[n+1], y1);
            y2 = fmaf(h[n+2], Cv[n+2], y2);
            y3 = fmaf(h[n+3], Cv[n+3], y3);
        }
        float yv = (y0 + y1) + (y2 + y3);
        float zv = zp[0];
        float sz = zv / (1.f + __expf(-zv));
        float res = fmaf(xv, Dd, yv) * sz;
        unsigned short hres = f2bf_rne(res);
        xh[0] = hres;
        xl[0] = f2bf_rne(res - bf2f(hres));
        dtp += DI; xh += DI; xl += DI; Bp += XD; zp += DI;
    }
}

// =====================================================================
// out = x + LayerNorm(m).  One 256-thread block per row (1024 cols).
// =====================================================================
__global__ __launch_bounds__(256) void ln_res(
    const float* __restrict__ x, const float* __restrict__ m,
    const float* __restrict__ w, const float* __restrict__ bb,
    float* __restrict__ out)
{
    int row = blockIdx.x;
    const float* mr = m + (size_t)row * DM;
    const float* xr = x + (size_t)row * DM;
    float*       op = out + (size_t)row * DM;

    float4 v = ((const float4*)mr)[threadIdx.x];
    float s = v.x + v.y + v.z + v.w;
    float q = v.x * v.x + v.y * v.y + v.z * v.z + v.w * v.w;
#pragma unroll
    for (int o = 32; o; o >>= 1) { s += __shfl_down(s, o); q += __shfl_down(q, o); }

    __shared__ float sred[4], qred[4];
    int wid = threadIdx.x >> 6, lane = threadIdx.x & 63;
    if (lane == 0) { sred[wid] = s; qred[wid] = q; }
    __syncthreads();
    s = sred[0] + sred[1] + sred[2] + sred[3];
    q = qred[0] + qred[1] + qred[2] + qred[3];

    float mu  = s * (1.f / DM);
    float var = q * (1.f / DM) - mu * mu;
    float rs  = rsqrtf(var + 1e-6f);

    float4 xv = ((const float4*)xr)[threadIdx.x];
    float4 wv = ((const float4*)w)[threadIdx.x];
    float4 bv = ((const float4*)bb)[threadIdx.x];
    float4 o;
    o.x = xv.x + (v.x - mu) * rs * wv.x + bv.x;
    o.y = xv.y + (v.y - mu) * rs * wv.y + bv.y;
    o.z = xv.z + (v.z - mu) * rs * wv.z + bv.z;
    o.w = xv.w + (v.w - mu) * rs * wv.w + bv.w;
    ((float4*)op)[threadIdx.x] = o;
}

// =====================================================================
extern "C" void kernel_launch(void* const* d_in, const int* in_sizes, int n_in,
                              void* d_out, int out_size, void* d_ws, size_t ws_size,
                              hipStream_t stream)
{
    const float* x        = (const float*)d_in[0];
    const float* in_w     = (const float*)d_in[1];
    const float* conv_w   = (const float*)d_in[2];
    const float* conv_b   = (const float*)d_in[3];
    const float* xproj_w  = (const float*)d_in[4];
    const float* dtproj_w = (const float*)d_in[5];
    const float* dtproj_b = (const float*)d_in[6];
    const float* A_log    = (const float*)d_in[7];
    const float* Dp       = (const float*)d_in[8];
    const float* out_w    = (const float*)d_in[9];
    const float* ln_w     = (const float*)d_in[10];
    const float* ln_b     = (const float*)d_in[11];
    float* out = (float*)d_out;

    // ---- Workspace layout (peak 135,790,592 B == R1-proven footprint) ----
    // [0, 33.55M)      bufX (w:in_proj, r:conv)   -> dtb (w:dt_proj, r:scan)
    // [33.55M, 67.11M) bufZ (w:in_proj, r:scanC)  -> mb@33.55M (w:out_proj,
    //                  r:ln) + We_o_hi@50.33M + We_o_lo@54.53M (w,r:step7)
    // [67.11M, 100.66M) Xhi, Xlo (conv out; y after scanC; r:out_proj)
    // [100.66M, 134.22M) Xe_hi/Xe_lo/Wi_hi/Wi_lo (w:1, r:2, then dead)
    //                  -> xpart@100.66M, Wx@113.25M, dA@114.29M, Wd@115.34M
    //                     (steps 4-5, dead before scan)
    //                  -> Psum@100.66M, Hsum@117.44M (16.78M each, scan)
    //                  [R6 BUG FIXED: Psum/Hsum overlapped by 8M and Hsum
    //                   ran past ws_size -> NaN. Now disjoint, in-bounds.]
    // [134.22M, 135.79M) xdbl [4096][96] f32 (w:4c, r:5a/6a/6c)
    char* ws = (char*)d_ws;
    float* bufX = (float*)ws;
    float* dtb  = (float*)ws;
    float* bufZ = (float*)(ws + 33554432);
    float* mb   = (float*)(ws + 33554432);
    unsigned short* We_o_hi = (unsigned short*)(ws + 50331648);
    unsigned short* We_o_lo = (unsigned short*)(ws + 54525952);
    unsigned short* Xhi  = (unsigned short*)(ws + 67108864);
    unsigned short* Xlo  = (unsigned short*)(ws + 83886080);
    unsigned short* Xe_hi = (unsigned short*)(ws + 100663296);
    unsigned short* Xe_lo = (unsigned short*)(ws + 109051904);
    unsigned short* Wi_hi = (unsigned short*)(ws + 117440512);
    unsigned short* Wi_lo = (unsigned short*)(ws + 125829120);
    float* xpart = (float*)(ws + 100663296);           // [8][4096][96] 12.58M
    unsigned short* Wx_hi = (unsigned short*)(ws + 113246208);  // [128][2048]
    unsigned short* Wx_lo = (unsigned short*)(ws + 113770496);
    unsigned short* dA_hi = (unsigned short*)(ws + 114294784);  // [4096][64]
    unsigned short* dA_lo = (unsigned short*)(ws + 114819072);
    unsigned short* Wd_hi = (unsigned short*)(ws + 115343360);  // [2048][64]
    unsigned short* Wd_lo = (unsigned short*)(ws + 115605504);
    float* Psum = (float*)(ws + 100663296);            // 16.78M, scan only
    float* Hsum = (float*)(ws + 117440512);            // 16.78M, scan only
    float* xdbl = (float*)(ws + 134217728);            // 1.57M tail

    const int M = NB * LQ;  // 4096

    // 1. split x, in_w to bf16 hi/lo
    split2<<<M * DM / 1024, 256, 0, stream>>>(x, Xe_hi, Xe_lo, DM);
    split2<<<(2 * DI) * DM / 1024, 256, 0, stream>>>(in_w, Wi_hi, Wi_lo, DM);

    // 2. in_proj MFMA (K'=3*1024), epilogue deinterleaves x|z
    gemm_mfma3<1><<<dim3((2*DI)/128, M/128), 256, 0, stream>>>(
        Xe_hi, Xe_lo, Wi_hi, Wi_lo, bufX, bufZ, nullptr, DM, 48, 0);

    // 3. conv + silu -> x as bf16 hi/lo (Xe/Wi dead)
    conv_silu2<<<(M * DI) / 256, 256, 0, stream>>>(bufX, conv_w, conv_b, Xhi, Xlo);

    // 4. x_proj MFMA, N pad 96->128, split-K=8 (bufX dead)
    split2_pad<<<dim3(DI/1024, 128), 256, 0, stream>>>(xproj_w, Wx_hi, Wx_lo, DI, XD);
    gemm_mfma3<2><<<dim3(1, M/128, 8), 256, 0, stream>>>(
        Xhi, Xlo, Wx_hi, Wx_lo, xpart, nullptr, nullptr, DI, 12, 0);
    reduce8<<<(M * XD) / 256, 256, 0, stream>>>(xpart, xdbl);

    // 5. dt_proj MFMA (K'=3*64) + softplus + bias
    split2_dtA<<<(M * RK) / 256, 256, 0, stream>>>(xdbl, dA_hi, dA_lo);
    split2<<<DI * RK / 1024, 256, 0, stream>>>(dtproj_w, Wd_hi, Wd_lo, RK);
    gemm_mfma3<3><<<dim3(DI/128, M/128), 256, 0, stream>>>(
        dA_hi, dA_lo, Wd_hi, Wd_lo, dtb, nullptr, dtproj_b, RK, 3, 0);

    // 6. chunked SSM scan; y overwrites Xhi/Xlo in place
    scan_phase_a<<<NB*CCH*8, 256, 0, stream>>>(dtb, xdbl, Xhi, Xlo, A_log, Psum, Hsum);
    scan_phase_b<<<(NB*DI*NS)/256, 256, 0, stream>>>(Psum, Hsum);
    scan_phase_c<<<NB*CCH*8, 256, 0, stream>>>(dtb, xdbl, Xhi, Xlo, bufZ,
                                               A_log, Dp, Hsum);

    // 7. out_proj MFMA (K'=3*2048); y already split as Xhi/Xlo (bufZ dead)
    split2<<<DM * DI / 1024, 256, 0, stream>>>(out_w, We_o_hi, We_o_lo, DI);
    gemm_mfma3<0><<<dim3(DM/128, M/128), 256, 0, stream>>>(
        Xhi, Xlo, We_o_hi, We_o_lo, mb, nullptr, nullptr, DI, 96, DM);

    // 8. out = x + LayerNorm(m)
    ln_res<<<M, 256, 0, stream>>>(x, mb, ln_w, ln_b, out);
}

// Round 8
// 509.213 us; speedup vs baseline: 4.9080x; 1.1033x over previous
//
#include <hip/hip_runtime.h>
#include <math.h>

// Problem constants (match reference)
#define DM   1024   // d_model
#define DI   2048   // d_inner
#define NS   16     // d_state
#define RK   64     // dt_rank
#define LQ   2048   // seq len
#define NB   2      // batch
#define XD   96     // dt_rank + 2*d_state
#define CCH  64     // scan chunks
#define CLEN 32     // LQ / CCH

typedef __attribute__((ext_vector_type(8))) short short8;
typedef __attribute__((ext_vector_type(4))) float f32x4;

#define UNPACK16(dst, ptr) do {                               \
    const float4* q_ = (const float4*)(ptr);                  \
    float4 q0=q_[0],q1=q_[1],q2=q_[2],q3=q_[3];               \
    dst[0]=q0.x; dst[1]=q0.y; dst[2]=q0.z; dst[3]=q0.w;       \
    dst[4]=q1.x; dst[5]=q1.y; dst[6]=q1.z; dst[7]=q1.w;       \
    dst[8]=q2.x; dst[9]=q2.y; dst[10]=q2.z; dst[11]=q2.w;     \
    dst[12]=q3.x; dst[13]=q3.y; dst[14]=q3.z; dst[15]=q3.w;   \
} while(0)

__device__ __forceinline__ unsigned short f2bf_rne(float f) {
    unsigned b = __float_as_uint(f);
    unsigned r = (b + 0x7fffu + ((b >> 16) & 1u)) >> 16;
    return (unsigned short)r;
}
__device__ __forceinline__ float bf2f(unsigned short u) {
    return __uint_as_float(((unsigned)u) << 16);
}

// =====================================================================
// split2: fp32 [R][K] -> bf16 hi[R][K] + lo[R][K]  (hi+lo ~= fp32).
// =====================================================================
__global__ __launch_bounds__(256) void split2(
    const float* __restrict__ s, unsigned short* __restrict__ hi,
    unsigned short* __restrict__ lo, int K)
{
    int idx = blockIdx.x * 256 + threadIdx.x;
    int c4 = idx % (K / 4);
    int r  = idx / (K / 4);
    float4 v = ((const float4*)(s + (size_t)r * K))[c4];
    unsigned short h0 = f2bf_rne(v.x), h1 = f2bf_rne(v.y),
                   h2 = f2bf_rne(v.z), h3 = f2bf_rne(v.w);
    unsigned short e0 = f2bf_rne(v.x - bf2f(h0)), e1 = f2bf_rne(v.y - bf2f(h1)),
                   e2 = f2bf_rne(v.z - bf2f(h2)), e3 = f2bf_rne(v.w - bf2f(h3));
    ((ushort4*)(hi + (size_t)r * K))[c4] = make_ushort4(h0, h1, h2, h3);
    ((ushort4*)(lo + (size_t)r * K))[c4] = make_ushort4(e0, e1, e2, e3);
}

// hi-only convert (for the 2-term out_proj weight)
__global__ __launch_bounds__(256) void cvt_hi(
    const float* __restrict__ s, unsigned short* __restrict__ hi)
{
    int c4 = blockIdx.x * 256 + threadIdx.x;
    float4 v = ((const float4*)s)[c4];
    ((ushort4*)hi)[c4] = make_ushort4(f2bf_rne(v.x), f2bf_rne(v.y),
                                      f2bf_rne(v.z), f2bf_rne(v.w));
}

// x_proj weight, padded 96 -> 128 rows (pad rows = 0). grid (K/1024, 128).
__global__ __launch_bounds__(256) void split2_pad(
    const float* __restrict__ s, unsigned short* __restrict__ hi,
    unsigned short* __restrict__ lo, int K, int rValid)
{
    int c4 = blockIdx.x * 256 + threadIdx.x;
    int r  = blockIdx.y;
    float4 v = make_float4(0.f, 0.f, 0.f, 0.f);
    if (r < rValid) v = ((const float4*)(s + (size_t)r * K))[c4];
    unsigned short h0 = f2bf_rne(v.x), h1 = f2bf_rne(v.y),
                   h2 = f2bf_rne(v.z), h3 = f2bf_rne(v.w);
    unsigned short e0 = f2bf_rne(v.x - bf2f(h0)), e1 = f2bf_rne(v.y - bf2f(h1)),
                   e2 = f2bf_rne(v.z - bf2f(h2)), e3 = f2bf_rne(v.w - bf2f(h3));
    ((ushort4*)(hi + (size_t)r * K))[c4] = make_ushort4(h0, h1, h2, h3);
    ((ushort4*)(lo + (size_t)r * K))[c4] = make_ushort4(e0, e1, e2, e3);
}

// dt A-operand: xdbl[:, :64] (row stride XD=96) -> hi/lo [4096][64]. grid 1024.
__global__ __launch_bounds__(256) void split2_dtA(
    const float* __restrict__ xdbl, unsigned short* __restrict__ hi,
    unsigned short* __restrict__ lo)
{
    int idx = blockIdx.x * 256 + threadIdx.x;   // over 4096*64
    int r = idx >> 6, c = idx & 63;
    float v = xdbl[(size_t)r * XD + c];
    unsigned short h = f2bf_rne(v);
    unsigned short e = f2bf_rne(v - bf2f(h));
    hi[(size_t)r * 64 + c] = h;
    lo[(size_t)r * 64 + c] = e;
}

// =====================================================================
// bf16 MFMA GEMM on hi/lo pairs:  C = A * W^T.
// NTERM=3: logical K'=3K, blocks [Ah|Ah|Al] x [Wh|Wl|Wh]  (~fp32)
// NTERM=2: logical K'=2K, blocks [Ah|Al] x [Wh|Wh]        (W at bf16)
// 128x128 tile, BK=64, 4 waves, 16x16x32 MFMA, global_load_lds(16B),
// pre-swizzled global source + XOR-swizzled ds_read (rule 21).
// EPI: 0 plain C0[ldc]; 1 split x/z (in_proj); 2 x_proj split-K partials
//      (col<96); 3 softplus+bias (dt_proj); 4 out_proj split-K partials
//      (z<2 -> C0, else C1; row offset (z&1)*M).
// =====================================================================
__device__ __forceinline__ void gl16(const unsigned short* g, unsigned short* l) {
    __builtin_amdgcn_global_load_lds(
        (const __attribute__((address_space(1))) unsigned int*)g,
        (__attribute__((address_space(3))) unsigned int*)l, 16, 0, 0);
}

template<int EPI, int NTERM>
__global__ __launch_bounds__(256) void gemm_mfma3(
    const unsigned short* __restrict__ Ahi, const unsigned short* __restrict__ Alo,
    const unsigned short* __restrict__ Whi, const unsigned short* __restrict__ Wlo,
    float* __restrict__ C0, float* __restrict__ C1,
    const float* __restrict__ bias, int K, int nkt_per, int ldc)
{
    __shared__ unsigned short Asm[128 * 64];   // [row][64] bf16, 128B rows
    __shared__ unsigned short Bsm[128 * 64];

    const int tid = threadIdx.x;
    const int l   = tid & 63;
    const int w   = tid >> 6;            // wave 0..3
    const int wr  = w >> 1, wc = w & 1;  // 2x2 wave grid (64x64 each)
    const int bm  = blockIdx.y * 128, bn = blockIdx.x * 128;
    const int ktpb = K >> 6;             // K-tiles per hi/lo block
    const int kt0  = blockIdx.z * nkt_per;

    f32x4 acc[4][4];
#pragma unroll
    for (int m = 0; m < 4; ++m)
#pragma unroll
        for (int n = 0; n < 4; ++n) acc[m][n] = (f32x4){0.f, 0.f, 0.f, 0.f};

    const int lr = l >> 3;
    const int ls = (l & 7) ^ lr;         // inverse-swizzled source slot
    const size_t roA = (size_t)(bm + w * 32 + lr) * K + ls * 8;
    const size_t roB = (size_t)(bn + w * 32 + lr) * K + ls * 8;

    const int offk0 = ((l >> 4) * 16) ^ ((l & 7) << 4);
    const int offk1 = (64 + (l >> 4) * 16) ^ ((l & 7) << 4);
    const int arow  = (l & 15);

    for (int i = 0; i < nkt_per; ++i) {
        const int kt  = kt0 + i;
        const int blk = kt / ktpb;
        const size_t kof = (size_t)(kt - blk * ktpb) * 64;
        const unsigned short* Ab;
        const unsigned short* Wb;
        if (NTERM == 3) {
            Ab = (blk < 2)  ? Ahi : Alo;
            Wb = (blk == 1) ? Wlo : Whi;
        } else {
            Ab = (blk == 0) ? Ahi : Alo;
            Wb = Whi;
        }
#pragma unroll
        for (int j = 0; j < 4; ++j) {
            gl16(Ab + roA + (size_t)j * 8 * K + kof, Asm + (w * 32 + j * 8) * 64);
            gl16(Wb + roB + (size_t)j * 8 * K + kof, Bsm + (w * 32 + j * 8) * 64);
        }
        __syncthreads();   // drains vmcnt -> staged data visible

#pragma unroll
        for (int kk = 0; kk < 2; ++kk) {
            const int offk = kk ? offk1 : offk0;
            short8 af[4], bf[4];
#pragma unroll
            for (int m = 0; m < 4; ++m)
                af[m] = *(const short8*)((const char*)Asm +
                         ((wr * 64 + m * 16 + arow) << 7) + offk);
#pragma unroll
            for (int n = 0; n < 4; ++n)
                bf[n] = *(const short8*)((const char*)Bsm +
                         ((wc * 64 + n * 16 + arow) << 7) + offk);
#pragma unroll
            for (int m = 0; m < 4; ++m)
#pragma unroll
                for (int n = 0; n < 4; ++n)
                    acc[m][n] = __builtin_amdgcn_mfma_f32_16x16x32_bf16(
                        af[m], bf[n], acc[m][n], 0, 0, 0);
        }
        __syncthreads();
    }

    // Epilogue: C row=(l>>4)*4+j, col=l&15 per 16x16 fragment
#pragma unroll
    for (int m = 0; m < 4; ++m) {
        int row = bm + wr * 64 + m * 16 + ((l >> 4) << 2);
#pragma unroll
        for (int n = 0; n < 4; ++n) {
            int col = bn + wc * 64 + n * 16 + (l & 15);
#pragma unroll
            for (int j = 0; j < 4; ++j) {
                float v = acc[m][n][j];
                size_t r = (size_t)(row + j);
                if (EPI == 0) {
                    C0[r * ldc + col] = v;
                } else if (EPI == 1) {          // in_proj: split x | z
                    if (col < DI) C0[r * DI + col]        = v;
                    else          C1[r * DI + (col - DI)] = v;
                } else if (EPI == 2) {          // x_proj: split-K partials
                    if (col < XD)
                        C0[((size_t)blockIdx.z * (NB * LQ) + r) * XD + col] = v;
                } else if (EPI == 3) {          // dt_proj: softplus + bias
                    v += bias[col];
                    v = (v > 20.f) ? v : log1pf(__expf(v));
                    C0[r * DI + col] = v;
                } else {                        // out_proj: split-K partials
                    float* Cz = (blockIdx.z < 2) ? C0 : C1;
                    Cz[((size_t)(blockIdx.z & 1) * (NB * LQ) + r) * ldc + col] = v;
                }
            }
        }
    }
}

// reduce 16 split-K partials -> xdbl [4096][96]
__global__ __launch_bounds__(256) void reduce16(
    const float* __restrict__ part, float* __restrict__ xdbl)
{
    int idx = blockIdx.x * 256 + threadIdx.x;   // over 4096*96
    float s = 0.f;
#pragma unroll
    for (int k = 0; k < 16; ++k) s += part[(size_t)k * (NB * LQ) * XD + idx];
    xdbl[idx] = s;
}

// =====================================================================
// Depthwise causal conv (k=4) + bias + silu; emits bf16 hi/lo of result.
// =====================================================================
__global__ __launch_bounds__(256) void conv_silu2(
    const float* __restrict__ bx, const float* __restrict__ cw,
    const float* __restrict__ cb, unsigned short* __restrict__ xhi,
    unsigned short* __restrict__ xlo)
{
    int idx = blockIdx.x * 256 + threadIdx.x;      // over 4096*2048
    int d = idx & (DI - 1);
    int t = idx >> 11;                             // token
    int l = t & (LQ - 1);
    float acc = cb[d];
#pragma unroll
    for (int k = 0; k < 4; ++k) {
        int ls = l - 3 + k;
        if (ls >= 0) acc = fmaf(bx[(size_t)(t - 3 + k) * DI + d], cw[d * 4 + k], acc);
    }
    float y = acc / (1.f + __expf(-acc));          // silu
    unsigned short h = f2bf_rne(y);
    xhi[idx] = h;
    xlo[idx] = f2bf_rne(y - bf2f(h));
}

// =====================================================================
// Chunked scan (A/B/C), x read as hi+lo — verified R7 structure.
// =====================================================================
__global__ __launch_bounds__(256) void scan_phase_a(
    const float* __restrict__ dt, const float* __restrict__ xdbl,
    const unsigned short* __restrict__ xhi, const unsigned short* __restrict__ xlo,
    const float* __restrict__ A_log, float* __restrict__ P, float* __restrict__ Hs)
{
    int blk = blockIdx.x;
    int dg  = blk & 7;
    int c   = (blk >> 3) & (CCH - 1);
    int b   = blk >> 9;
    int d   = dg * 256 + (int)threadIdx.x;
    int l0  = c * CLEN;

    float Aa[NS];
    {
        float tmp[NS];
        UNPACK16(tmp, A_log + d * NS);
#pragma unroll
        for (int n = 0; n < NS; ++n) Aa[n] = -__expf(tmp[n]);
    }
    float h[NS], Pr[NS];
#pragma unroll
    for (int n = 0; n < NS; ++n) { h[n] = 0.f; Pr[n] = 1.f; }

    size_t base = ((size_t)b * LQ + l0) * DI + d;
    const float* dtp = dt + base;
    const unsigned short* xh = xhi + base;
    const unsigned short* xl = xlo + base;
    const float* Bp  = xdbl + ((size_t)b * LQ + l0) * XD + RK;

    for (int l = 0; l < CLEN; ++l) {
        float dtv = dtp[0];
        float xv  = bf2f(xh[0]) + bf2f(xl[0]);
        float dtx = dtv * xv;
        float Bv[NS];
        UNPACK16(Bv, Bp);
#pragma unroll
        for (int n = 0; n < NS; ++n) {
            float a = __expf(dtv * Aa[n]);
            Pr[n] *= a;
            h[n] = fmaf(h[n], a, dtx * Bv[n]);
        }
        dtp += DI; xh += DI; xl += DI; Bp += XD;
    }

    size_t off = (((size_t)b * CCH + c) * DI + d) * NS;
    float4* Pd = (float4*)(P + off);
    float4* Hd = (float4*)(Hs + off);
    Pd[0] = make_float4(Pr[0],  Pr[1],  Pr[2],  Pr[3]);
    Pd[1] = make_float4(Pr[4],  Pr[5],  Pr[6],  Pr[7]);
    Pd[2] = make_float4(Pr[8],  Pr[9],  Pr[10], Pr[11]);
    Pd[3] = make_float4(Pr[12], Pr[13], Pr[14], Pr[15]);
    Hd[0] = make_float4(h[0],  h[1],  h[2],  h[3]);
    Hd[1] = make_float4(h[4],  h[5],  h[6],  h[7]);
    Hd[2] = make_float4(h[8],  h[9],  h[10], h[11]);
    Hd[3] = make_float4(h[12], h[13], h[14], h[15]);
}

__global__ __launch_bounds__(256) void scan_phase_b(
    const float* __restrict__ P, float* __restrict__ Hs)
{
    int t = blockIdx.x * 256 + (int)threadIdx.x;    // NB*DI*NS = 65536
    size_t off = ((size_t)(t >> 15) * CCH) * (DI * NS) + (size_t)(t & 32767);
    float H = 0.f;
#pragma unroll 8
    for (int c = 0; c < CCH; ++c) {
        float Pv = P[off];
        float he = Hs[off];
        Hs[off] = H;
        H = fmaf(Pv, H, he);
        off += DI * NS;
    }
}

__global__ __launch_bounds__(256) void scan_phase_c(
    const float* __restrict__ dt, const float* __restrict__ xdbl,
    unsigned short* xhi, unsigned short* xlo, const float* __restrict__ bz,
    const float* __restrict__ A_log, const float* __restrict__ Dp,
    const float* __restrict__ Hs)
{
    int blk = blockIdx.x;
    int dg  = blk & 7;
    int c   = (blk >> 3) & (CCH - 1);
    int b   = blk >> 9;
    int d   = dg * 256 + (int)threadIdx.x;
    int l0  = c * CLEN;

    float Aa[NS];
    {
        float tmp[NS];
        UNPACK16(tmp, A_log + d * NS);
#pragma unroll
        for (int n = 0; n < NS; ++n) Aa[n] = -__expf(tmp[n]);
    }
    float Dd = Dp[d];

    float h[NS];
    UNPACK16(h, Hs + (((size_t)b * CCH + c) * DI + d) * NS);

    size_t base = ((size_t)b * LQ + l0) * DI + d;
    const float* dtp = dt + base;
    unsigned short* xh = xhi + base;
    unsigned short* xl = xlo + base;
    const float* Bp  = xdbl + ((size_t)b * LQ + l0) * XD + RK;
    const float* zp  = bz + base;

    for (int l = 0; l < CLEN; ++l) {
        float dtv = dtp[0];
        float xv  = bf2f(xh[0]) + bf2f(xl[0]);
        float dtx = dtv * xv;
        float Bv[NS], Cv[NS];
        UNPACK16(Bv, Bp);
        UNPACK16(Cv, Bp + NS);
        float y0 = 0.f, y1 = 0.f, y2 = 0.f, y3 = 0.f;
#pragma unroll
        for (int n = 0; n < NS; n += 4) {
            float a0 = __expf(dtv * Aa[n+0]);
            float a1 = __expf(dtv * Aa[n+1]);
            float a2 = __expf(dtv * Aa[n+2]);
            float a3 = __expf(dtv * Aa[n+3]);
            h[n+0] = fmaf(h[n+0], a0, dtx * Bv[n+0]);
            h[n+1] = fmaf(h[n+1], a1, dtx * Bv[n+1]);
            h[n+2] = fmaf(h[n+2], a2, dtx * Bv[n+2]);
            h[n+3] = fmaf(h[n+3], a3, dtx * Bv[n+3]);
            y0 = fmaf(h[n+0], Cv[n+0], y0);
            y1 = fmaf(h[n+1], Cv[n+1], y1);
            y2 = fmaf(h[n+2], Cv[n+2], y2);
            y3 = fmaf(h[n+3], Cv[n+3], y3);
        }
        float yv = (y0 + y1) + (y2 + y3);
        float zv = zp[0];
        float sz = zv / (1.f + __expf(-zv));
        float res = fmaf(xv, Dd, yv) * sz;
        unsigned short hres = f2bf_rne(res);
        xh[0] = hres;
        xl[0] = f2bf_rne(res - bf2f(hres));
        dtp += DI; xh += DI; xl += DI; Bp += XD; zp += DI;
    }
}

// =====================================================================
// out = x + LayerNorm(m0+m1+m2+m3)  (fused split-K reduction)
// =====================================================================
__global__ __launch_bounds__(256) void ln_res4(
    const float* __restrict__ x, const float* __restrict__ m01,
    const float* __restrict__ m23, const float* __restrict__ w,
    const float* __restrict__ bb, float* __restrict__ out)
{
    int row = blockIdx.x;
    const size_t half = (size_t)(NB * LQ) * DM;     // partial stride (floats)
    const float* p0 = m01 + (size_t)row * DM;
    const float* p1 = m01 + half + (size_t)row * DM;
    const float* p2 = m23 + (size_t)row * DM;
    const float* p3 = m23 + half + (size_t)row * DM;
    const float* xr = x + (size_t)row * DM;
    float*       op = out + (size_t)row * DM;

    float4 a0 = ((const float4*)p0)[threadIdx.x];
    float4 a1 = ((const float4*)p1)[threadIdx.x];
    float4 a2 = ((const float4*)p2)[threadIdx.x];
    float4 a3 = ((const float4*)p3)[threadIdx.x];
    float4 v;
    v.x = (a0.x + a1.x) + (a2.x + a3.x);
    v.y = (a0.y + a1.y) + (a2.y + a3.y);
    v.z = (a0.z + a1.z) + (a2.z + a3.z);
    v.w = (a0.w + a1.w) + (a2.w + a3.w);

    float s = v.x + v.y + v.z + v.w;
    float q = v.x * v.x + v.y * v.y + v.z * v.z + v.w * v.w;
#pragma unroll
    for (int o = 32; o; o >>= 1) { s += __shfl_down(s, o); q += __shfl_down(q, o); }

    __shared__ float sred[4], qred[4];
    int wid = threadIdx.x >> 6, lane = threadIdx.x & 63;
    if (lane == 0) { sred[wid] = s; qred[wid] = q; }
    __syncthreads();
    s = sred[0] + sred[1] + sred[2] + sred[3];
    q = qred[0] + qred[1] + qred[2] + qred[3];

    float mu  = s * (1.f / DM);
    float var = q * (1.f / DM) - mu * mu;
    float rs  = rsqrtf(var + 1e-6f);

    float4 xv = ((const float4*)xr)[threadIdx.x];
    float4 wv = ((const float4*)w)[threadIdx.x];
    float4 bv = ((const float4*)bb)[threadIdx.x];
    float4 o;
    o.x = xv.x + (v.x - mu) * rs * wv.x + bv.x;
    o.y = xv.y + (v.y - mu) * rs * wv.y + bv.y;
    o.z = xv.z + (v.z - mu) * rs * wv.z + bv.z;
    o.w = xv.w + (v.w - mu) * rs * wv.w + bv.w;
    ((float4*)op)[threadIdx.x] = o;
}

// =====================================================================
extern "C" void kernel_launch(void* const* d_in, const int* in_sizes, int n_in,
                              void* d_out, int out_size, void* d_ws, size_t ws_size,
                              hipStream_t stream)
{
    const float* x        = (const float*)d_in[0];
    const float* in_w     = (const float*)d_in[1];
    const float* conv_w   = (const float*)d_in[2];
    const float* conv_b   = (const float*)d_in[3];
    const float* xproj_w  = (const float*)d_in[4];
    const float* dtproj_w = (const float*)d_in[5];
    const float* dtproj_b = (const float*)d_in[6];
    const float* A_log    = (const float*)d_in[7];
    const float* Dp       = (const float*)d_in[8];
    const float* out_w    = (const float*)d_in[9];
    const float* ln_w     = (const float*)d_in[10];
    const float* ln_b     = (const float*)d_in[11];
    float* out = (float*)d_out;

    // ---- Workspace layout (peak 135,790,592 B, same proven footprint) ----
    // [0, 33.55M)       bufX (w:2, r:3) -> dtb (w:5, r:6) -> We_o_hi@0 (w:7a)
    // [33.55M, 67.11M)  bufZ (w:2, r:6c) -> mb01 (out_proj partials z=0,1)
    // [67.11M, 100.66M) Xhi, Xlo (w:3; y after 6c; r:7b)
    // [100.66M, 134.22M) Xe/Wi (w:1, r:2) -> xpart@100.66M(25.2M) +
    //                   Wx/dA/Wd @125.83M.. (steps 4-5) -> Psum@100.66M,
    //                   Hsum@117.44M (scan) -> mb23 (out_proj partials z=2,3)
    // [134.22M, 135.79M) xdbl [4096][96] f32 (w:4, r:5/6)
    char* ws = (char*)d_ws;
    float* bufX = (float*)ws;
    float* dtb  = (float*)ws;
    unsigned short* We_o_hi = (unsigned short*)ws;      // 4.2M, after scan
    float* bufZ = (float*)(ws + 33554432);
    float* mb01 = (float*)(ws + 33554432);              // 2 x 16.78M
    unsigned short* Xhi  = (unsigned short*)(ws + 67108864);
    unsigned short* Xlo  = (unsigned short*)(ws + 83886080);
    unsigned short* Xe_hi = (unsigned short*)(ws + 100663296);
    unsigned short* Xe_lo = (unsigned short*)(ws + 109051904);
    unsigned short* Wi_hi = (unsigned short*)(ws + 117440512);
    unsigned short* Wi_lo = (unsigned short*)(ws + 125829120);
    float* xpart = (float*)(ws + 100663296);            // [16][4096][96] 25.2M
    unsigned short* Wx_hi = (unsigned short*)(ws + 125829120);  // [128][2048]
    unsigned short* Wx_lo = (unsigned short*)(ws + 126353408);
    unsigned short* dA_hi = (unsigned short*)(ws + 126877696);  // [4096][64]
    unsigned short* dA_lo = (unsigned short*)(ws + 127401984);
    unsigned short* Wd_hi = (unsigned short*)(ws + 127926272);  // [2048][64]
    unsigned short* Wd_lo = (unsigned short*)(ws + 128188416);
    float* Psum = (float*)(ws + 100663296);             // 16.78M (scan)
    float* Hsum = (float*)(ws + 117440512);             // 16.78M (scan)
    float* mb23 = (float*)(ws + 100663296);             // 2 x 16.78M, after scan
    float* xdbl = (float*)(ws + 134217728);             // 1.57M tail

    const int M = NB * LQ;  // 4096

    // 1. split x, in_w to bf16 hi/lo
    split2<<<M * DM / 1024, 256, 0, stream>>>(x, Xe_hi, Xe_lo, DM);
    split2<<<(2 * DI) * DM / 1024, 256, 0, stream>>>(in_w, Wi_hi, Wi_lo, DM);

    // 2. in_proj MFMA (3-term, K'=3*1024), epilogue deinterleaves x|z
    gemm_mfma3<1,3><<<dim3((2*DI)/128, M/128), 256, 0, stream>>>(
        Xe_hi, Xe_lo, Wi_hi, Wi_lo, bufX, bufZ, nullptr, DM, 48, 0);

    // 3. conv + silu -> x as bf16 hi/lo (Xe/Wi dead)
    conv_silu2<<<(M * DI) / 256, 256, 0, stream>>>(bufX, conv_w, conv_b, Xhi, Xlo);

    // 4. x_proj MFMA (3-term), N pad 96->128, split-K=16 (bufX dead)
    split2_pad<<<dim3(DI/1024, 128), 256, 0, stream>>>(xproj_w, Wx_hi, Wx_lo, DI, XD);
    gemm_mfma3<2,3><<<dim3(1, M/128, 16), 256, 0, stream>>>(
        Xhi, Xlo, Wx_hi, Wx_lo, xpart, nullptr, nullptr, DI, 6, 0);
    reduce16<<<(M * XD) / 256, 256, 0, stream>>>(xpart, xdbl);

    // 5. dt_proj MFMA (3-term, K'=3*64) + softplus + bias
    split2_dtA<<<(M * RK) / 256, 256, 0, stream>>>(xdbl, dA_hi, dA_lo);
    split2<<<DI * RK / 1024, 256, 0, stream>>>(dtproj_w, Wd_hi, Wd_lo, RK);
    gemm_mfma3<3,3><<<dim3(DI/128, M/128), 256, 0, stream>>>(
        dA_hi, dA_lo, Wd_hi, Wd_lo, dtb, nullptr, dtproj_b, RK, 3, 0);

    // 6. chunked SSM scan; y overwrites Xhi/Xlo in place
    scan_phase_a<<<NB*CCH*8, 256, 0, stream>>>(dtb, xdbl, Xhi, Xlo, A_log, Psum, Hsum);
    scan_phase_b<<<(NB*DI*NS)/256, 256, 0, stream>>>(Psum, Hsum);
    scan_phase_c<<<NB*CCH*8, 256, 0, stream>>>(dtb, xdbl, Xhi, Xlo, bufZ,
                                               A_log, Dp, Hsum);

    // 7. out_proj MFMA: 2-term ((Ah+Al)*Wh), split-K=4 -> 1024 blocks.
    //    (dtb, bufZ, Psum, Hsum all dead now.)
    cvt_hi<<<DM * DI / 1024, 256, 0, stream>>>(out_w, We_o_hi);
    gemm_mfma3<4,2><<<dim3(DM/128, M/128, 4), 256, 0, stream>>>(
        Xhi, Xlo, We_o_hi, We_o_hi, mb01, mb23, nullptr, DI, 16, DM);

    // 8. out = x + LayerNorm(sum of 4 partials)
    ln_res4<<<M, 256, 0, stream>>>(x, mb01, mb23, ln_w, ln_b, out);
}

// Round 9
// 399.715 us; speedup vs baseline: 6.2524x; 1.2739x over previous
//
#include <hip/hip_runtime.h>
#include <math.h>

// Problem constants (match reference)
#define DM   1024   // d_model
#define DI   2048   // d_inner
#define NS   16     // d_state
#define RK   64     // dt_rank
#define LQ   2048   // seq len
#define NB   2      // batch
#define XD   96     // dt_rank + 2*d_state
#define CCH  64     // scan chunks
#define CLEN 32     // LQ / CCH

typedef __attribute__((ext_vector_type(8))) _Float16 half8;
typedef __attribute__((ext_vector_type(4))) _Float16 half4;
typedef __attribute__((ext_vector_type(4))) float f32x4;

#define UNPACK16(dst, ptr) do {                               \
    const float4* q_ = (const float4*)(ptr);                  \
    float4 q0=q_[0],q1=q_[1],q2=q_[2],q3=q_[3];               \
    dst[0]=q0.x; dst[1]=q0.y; dst[2]=q0.z; dst[3]=q0.w;       \
    dst[4]=q1.x; dst[5]=q1.y; dst[6]=q1.z; dst[7]=q1.w;       \
    dst[8]=q2.x; dst[9]=q2.y; dst[10]=q2.z; dst[11]=q2.w;     \
    dst[12]=q3.x; dst[13]=q3.y; dst[14]=q3.z; dst[15]=q3.w;   \
} while(0)

// =====================================================================
// cvt: fp32 [N] -> fp16 [N], 4 elems/thread (flat)
// =====================================================================
__global__ __launch_bounds__(256) void cvt_h(
    const float* __restrict__ s, _Float16* __restrict__ d)
{
    int c4 = blockIdx.x * 256 + threadIdx.x;
    float4 v = ((const float4*)s)[c4];
    half4 o = {(_Float16)v.x, (_Float16)v.y, (_Float16)v.z, (_Float16)v.w};
    ((half4*)d)[c4] = o;
}

// x_proj weight, padded 96 -> 128 rows (pad rows = 0). grid (K/1024, 128).
__global__ __launch_bounds__(256) void cvt_h_pad(
    const float* __restrict__ s, _Float16* __restrict__ d, int K, int rValid)
{
    int c4 = blockIdx.x * 256 + threadIdx.x;
    int r  = blockIdx.y;
    float4 v = make_float4(0.f, 0.f, 0.f, 0.f);
    if (r < rValid) v = ((const float4*)(s + (size_t)r * K))[c4];
    half4 o = {(_Float16)v.x, (_Float16)v.y, (_Float16)v.z, (_Float16)v.w};
    ((half4*)(d + (size_t)r * K))[c4] = o;
}

// dt A-operand: xdbl[:, :64] (row stride XD=96) -> fp16 [4096][64]. grid 1024.
__global__ __launch_bounds__(256) void cvt_h_dtA(
    const float* __restrict__ xdbl, _Float16* __restrict__ d)
{
    int idx = blockIdx.x * 256 + threadIdx.x;   // over 4096*64
    int r = idx >> 6, c = idx & 63;
    d[(size_t)r * 64 + c] = (_Float16)xdbl[(size_t)r * XD + c];
}

// =====================================================================
// fp16 MFMA GEMM:  C[M][N] f32 = A[M][K] * W[N][K]^T   (single pass,
// ~2^-11 relative accuracy). 128x128 tile, BK=64, 4 waves (2x2 of
// 64x64), 16x16x32_f16 MFMA, global_load_lds(16B), pre-swizzled global
// source + XOR-swizzled ds_read (rule 21, verified R5-R8 structure).
// EPI: 1 split x/z (in_proj); 2 x_proj split-K partials (col<96);
//      3 softplus+bias (dt_proj); 4 out_proj split-K partials (z-major).
// =====================================================================
__device__ __forceinline__ void gl16(const unsigned short* g, unsigned short* l) {
    __builtin_amdgcn_global_load_lds(
        (const __attribute__((address_space(1))) unsigned int*)g,
        (__attribute__((address_space(3))) unsigned int*)l, 16, 0, 0);
}

template<int EPI>
__global__ __launch_bounds__(256) void gemm_h(
    const unsigned short* __restrict__ A, const unsigned short* __restrict__ W,
    float* __restrict__ C0, float* __restrict__ C1,
    const float* __restrict__ bias, int K, int nkt_per, int ldc)
{
    __shared__ unsigned short Asm[128 * 64];   // [row][64] fp16, 128B rows
    __shared__ unsigned short Bsm[128 * 64];

    const int tid = threadIdx.x;
    const int l   = tid & 63;
    const int w   = tid >> 6;            // wave 0..3
    const int wr  = w >> 1, wc = w & 1;  // 2x2 wave grid (64x64 each)
    const int bm  = blockIdx.y * 128, bn = blockIdx.x * 128;
    const int kt0 = blockIdx.z * nkt_per;

    f32x4 acc[4][4];
#pragma unroll
    for (int m = 0; m < 4; ++m)
#pragma unroll
        for (int n = 0; n < 4; ++n) acc[m][n] = (f32x4){0.f, 0.f, 0.f, 0.f};

    const int lr = l >> 3;
    const int ls = (l & 7) ^ lr;         // inverse-swizzled source slot
    const unsigned short* ga = A + (size_t)(bm + w * 32 + lr) * K + ls * 8;
    const unsigned short* gb = W + (size_t)(bn + w * 32 + lr) * K + ls * 8;

    const int offk0 = ((l >> 4) * 16) ^ ((l & 7) << 4);
    const int offk1 = (64 + (l >> 4) * 16) ^ ((l & 7) << 4);
    const int arow  = (l & 15);

    for (int i = 0; i < nkt_per; ++i) {
        const size_t kof = (size_t)(kt0 + i) * 64;
#pragma unroll
        for (int j = 0; j < 4; ++j) {
            gl16(ga + (size_t)j * 8 * K + kof, Asm + (w * 32 + j * 8) * 64);
            gl16(gb + (size_t)j * 8 * K + kof, Bsm + (w * 32 + j * 8) * 64);
        }
        __syncthreads();   // drains vmcnt -> staged data visible

#pragma unroll
        for (int kk = 0; kk < 2; ++kk) {
            const int offk = kk ? offk1 : offk0;
            half8 af[4], bf[4];
#pragma unroll
            for (int m = 0; m < 4; ++m)
                af[m] = *(const half8*)((const char*)Asm +
                         ((wr * 64 + m * 16 + arow) << 7) + offk);
#pragma unroll
            for (int n = 0; n < 4; ++n)
                bf[n] = *(const half8*)((const char*)Bsm +
                         ((wc * 64 + n * 16 + arow) << 7) + offk);
#pragma unroll
            for (int m = 0; m < 4; ++m)
#pragma unroll
                for (int n = 0; n < 4; ++n)
                    acc[m][n] = __builtin_amdgcn_mfma_f32_16x16x32_f16(
                        af[m], bf[n], acc[m][n], 0, 0, 0);
        }
        __syncthreads();
    }

    // Epilogue: C row=(l>>4)*4+j, col=l&15 per 16x16 fragment
#pragma unroll
    for (int m = 0; m < 4; ++m) {
        int row = bm + wr * 64 + m * 16 + ((l >> 4) << 2);
#pragma unroll
        for (int n = 0; n < 4; ++n) {
            int col = bn + wc * 64 + n * 16 + (l & 15);
#pragma unroll
            for (int j = 0; j < 4; ++j) {
                float v = acc[m][n][j];
                size_t r = (size_t)(row + j);
                if (EPI == 1) {                 // in_proj: split x | z
                    if (col < DI) C0[r * DI + col]        = v;
                    else          C1[r * DI + (col - DI)] = v;
                } else if (EPI == 2) {          // x_proj: split-K partials
                    if (col < XD)
                        C0[((size_t)blockIdx.z * (NB * LQ) + r) * XD + col] = v;
                } else if (EPI == 3) {          // dt_proj: softplus + bias
                    v += bias[col];
                    v = (v > 20.f) ? v : log1pf(__expf(v));
                    C0[r * DI + col] = v;
                } else {                        // out_proj: split-K partials
                    C0[((size_t)blockIdx.z * (NB * LQ) + r) * ldc + col] = v;
                }
            }
        }
    }
}

// reduce 16 split-K partials -> xdbl [4096][96]
__global__ __launch_bounds__(256) void reduce16(
    const float* __restrict__ part, float* __restrict__ xdbl)
{
    int idx = blockIdx.x * 256 + threadIdx.x;   // over 4096*96
    float s = 0.f;
#pragma unroll
    for (int k = 0; k < 16; ++k) s += part[(size_t)k * (NB * LQ) * XD + idx];
    xdbl[idx] = s;
}

// =====================================================================
// Depthwise causal conv (k=4) + bias + silu; emits fp16 result.
// =====================================================================
__global__ __launch_bounds__(256) void conv_silu_h(
    const float* __restrict__ bx, const float* __restrict__ cw,
    const float* __restrict__ cb, _Float16* __restrict__ xh)
{
    int idx = blockIdx.x * 256 + threadIdx.x;      // over 4096*2048
    int d = idx & (DI - 1);
    int t = idx >> 11;                             // token
    int l = t & (LQ - 1);
    float acc = cb[d];
#pragma unroll
    for (int k = 0; k < 4; ++k) {
        int ls = l - 3 + k;
        if (ls >= 0) acc = fmaf(bx[(size_t)(t - 3 + k) * DI + d], cw[d * 4 + k], acc);
    }
    float y = acc / (1.f + __expf(-acc));          // silu
    xh[idx] = (_Float16)y;
}

// =====================================================================
// Chunked scan (A/B/C) — verified structure; x now a single fp16 array.
// =====================================================================
__global__ __launch_bounds__(256) void scan_phase_a(
    const float* __restrict__ dt, const float* __restrict__ xdbl,
    const _Float16* __restrict__ xhp, const float* __restrict__ A_log,
    float* __restrict__ P, float* __restrict__ Hs)
{
    int blk = blockIdx.x;
    int dg  = blk & 7;
    int c   = (blk >> 3) & (CCH - 1);
    int b   = blk >> 9;
    int d   = dg * 256 + (int)threadIdx.x;
    int l0  = c * CLEN;

    float Aa[NS];
    {
        float tmp[NS];
        UNPACK16(tmp, A_log + d * NS);
#pragma unroll
        for (int n = 0; n < NS; ++n) Aa[n] = -__expf(tmp[n]);
    }
    float h[NS], Pr[NS];
#pragma unroll
    for (int n = 0; n < NS; ++n) { h[n] = 0.f; Pr[n] = 1.f; }

    size_t base = ((size_t)b * LQ + l0) * DI + d;
    const float* dtp = dt + base;
    const _Float16* xp = xhp + base;
    const float* Bp  = xdbl + ((size_t)b * LQ + l0) * XD + RK;

    for (int l = 0; l < CLEN; ++l) {
        float dtv = dtp[0];
        float xv  = (float)xp[0];
        float dtx = dtv * xv;
        float Bv[NS];
        UNPACK16(Bv, Bp);
#pragma unroll
        for (int n = 0; n < NS; ++n) {
            float a = __expf(dtv * Aa[n]);
            Pr[n] *= a;
            h[n] = fmaf(h[n], a, dtx * Bv[n]);
        }
        dtp += DI; xp += DI; Bp += XD;
    }

    size_t off = (((size_t)b * CCH + c) * DI + d) * NS;
    float4* Pd = (float4*)(P + off);
    float4* Hd = (float4*)(Hs + off);
    Pd[0] = make_float4(Pr[0],  Pr[1],  Pr[2],  Pr[3]);
    Pd[1] = make_float4(Pr[4],  Pr[5],  Pr[6],  Pr[7]);
    Pd[2] = make_float4(Pr[8],  Pr[9],  Pr[10], Pr[11]);
    Pd[3] = make_float4(Pr[12], Pr[13], Pr[14], Pr[15]);
    Hd[0] = make_float4(h[0],  h[1],  h[2],  h[3]);
    Hd[1] = make_float4(h[4],  h[5],  h[6],  h[7]);
    Hd[2] = make_float4(h[8],  h[9],  h[10], h[11]);
    Hd[3] = make_float4(h[12], h[13], h[14], h[15]);
}

__global__ __launch_bounds__(256) void scan_phase_b(
    const float* __restrict__ P, float* __restrict__ Hs)
{
    int t = blockIdx.x * 256 + (int)threadIdx.x;    // NB*DI*NS = 65536
    size_t off = ((size_t)(t >> 15) * CCH) * (DI * NS) + (size_t)(t & 32767);
    float H = 0.f;
#pragma unroll 8
    for (int c = 0; c < CCH; ++c) {
        float Pv = P[off];
        float he = Hs[off];
        Hs[off] = H;
        H = fmaf(Pv, H, he);
        off += DI * NS;
    }
}

__global__ __launch_bounds__(256) void scan_phase_c(
    const float* __restrict__ dt, const float* __restrict__ xdbl,
    _Float16* xhp, const float* __restrict__ bz,
    const float* __restrict__ A_log, const float* __restrict__ Dp,
    const float* __restrict__ Hs)
{
    int blk = blockIdx.x;
    int dg  = blk & 7;
    int c   = (blk >> 3) & (CCH - 1);
    int b   = blk >> 9;
    int d   = dg * 256 + (int)threadIdx.x;
    int l0  = c * CLEN;

    float Aa[NS];
    {
        float tmp[NS];
        UNPACK16(tmp, A_log + d * NS);
#pragma unroll
        for (int n = 0; n < NS; ++n) Aa[n] = -__expf(tmp[n]);
    }
    float Dd = Dp[d];

    float h[NS];
    UNPACK16(h, Hs + (((size_t)b * CCH + c) * DI + d) * NS);

    size_t base = ((size_t)b * LQ + l0) * DI + d;
    const float* dtp = dt + base;
    _Float16* xp = xhp + base;
    const float* Bp  = xdbl + ((size_t)b * LQ + l0) * XD + RK;
    const float* zp  = bz + base;

    for (int l = 0; l < CLEN; ++l) {
        float dtv = dtp[0];
        float xv  = (float)xp[0];
        float dtx = dtv * xv;
        float Bv[NS], Cv[NS];
        UNPACK16(Bv, Bp);
        UNPACK16(Cv, Bp + NS);
        float y0 = 0.f, y1 = 0.f, y2 = 0.f, y3 = 0.f;
#pragma unroll
        for (int n = 0; n < NS; n += 4) {
            float a0 = __expf(dtv * Aa[n+0]);
            float a1 = __expf(dtv * Aa[n+1]);
            float a2 = __expf(dtv * Aa[n+2]);
            float a3 = __expf(dtv * Aa[n+3]);
            h[n+0] = fmaf(h[n+0], a0, dtx * Bv[n+0]);
            h[n+1] = fmaf(h[n+1], a1, dtx * Bv[n+1]);
            h[n+2] = fmaf(h[n+2], a2, dtx * Bv[n+2]);
            h[n+3] = fmaf(h[n+3], a3, dtx * Bv[n+3]);
            y0 = fmaf(h[n+0], Cv[n+0], y0);
            y1 = fmaf(h[n+1], Cv[n+1], y1);
            y2 = fmaf(h[n+2], Cv[n+2], y2);
            y3 = fmaf(h[n+3], Cv[n+3], y3);
        }
        float yv = (y0 + y1) + (y2 + y3);
        float zv = zp[0];
        float sz = zv / (1.f + __expf(-zv));
        float res = fmaf(xv, Dd, yv) * sz;
        xp[0] = (_Float16)res;
        dtp += DI; xp += DI; Bp += XD; zp += DI;
    }
}

// =====================================================================
// out = x + LayerNorm(m0+m1+m2+m3)  (fused out_proj split-K reduction)
// =====================================================================
__global__ __launch_bounds__(256) void ln_res4(
    const float* __restrict__ x, const float* __restrict__ mp,
    const float* __restrict__ w, const float* __restrict__ bb,
    float* __restrict__ out)
{
    int row = blockIdx.x;
    const size_t stride = (size_t)(NB * LQ) * DM;   // partial stride (floats)
    const float* p0 = mp + (size_t)row * DM;
    const float* xr = x + (size_t)row * DM;
    float*       op = out + (size_t)row * DM;

    float4 a0 = ((const float4*)p0)[threadIdx.x];
    float4 a1 = ((const float4*)(p0 + stride))[threadIdx.x];
    float4 a2 = ((const float4*)(p0 + 2 * stride))[threadIdx.x];
    float4 a3 = ((const float4*)(p0 + 3 * stride))[threadIdx.x];
    float4 v;
    v.x = (a0.x + a1.x) + (a2.x + a3.x);
    v.y = (a0.y + a1.y) + (a2.y + a3.y);
    v.z = (a0.z + a1.z) + (a2.z + a3.z);
    v.w = (a0.w + a1.w) + (a2.w + a3.w);

    float s = v.x + v.y + v.z + v.w;
    float q = v.x * v.x + v.y * v.y + v.z * v.z + v.w * v.w;
#pragma unroll
    for (int o = 32; o; o >>= 1) { s += __shfl_down(s, o); q += __shfl_down(q, o); }

    __shared__ float sred[4], qred[4];
    int wid = threadIdx.x >> 6, lane = threadIdx.x & 63;
    if (lane == 0) { sred[wid] = s; qred[wid] = q; }
    __syncthreads();
    s = sred[0] + sred[1] + sred[2] + sred[3];
    q = qred[0] + qred[1] + qred[2] + qred[3];

    float mu  = s * (1.f / DM);
    float var = q * (1.f / DM) - mu * mu;
    float rs  = rsqrtf(var + 1e-6f);

    float4 xv = ((const float4*)xr)[threadIdx.x];
    float4 wv = ((const float4*)w)[threadIdx.x];
    float4 bv = ((const float4*)bb)[threadIdx.x];
    float4 o;
    o.x = xv.x + (v.x - mu) * rs * wv.x + bv.x;
    o.y = xv.y + (v.y - mu) * rs * wv.y + bv.y;
    o.z = xv.z + (v.z - mu) * rs * wv.z + bv.z;
    o.w = xv.w + (v.w - mu) * rs * wv.w + bv.w;
    ((float4*)op)[threadIdx.x] = o;
}

// =====================================================================
extern "C" void kernel_launch(void* const* d_in, const int* in_sizes, int n_in,
                              void* d_out, int out_size, void* d_ws, size_t ws_size,
                              hipStream_t stream)
{
    const float* x        = (const float*)d_in[0];
    const float* in_w     = (const float*)d_in[1];
    const float* conv_w   = (const float*)d_in[2];
    const float* conv_b   = (const float*)d_in[3];
    const float* xproj_w  = (const float*)d_in[4];
    const float* dtproj_w = (const float*)d_in[5];
    const float* dtproj_b = (const float*)d_in[6];
    const float* A_log    = (const float*)d_in[7];
    const float* Dp       = (const float*)d_in[8];
    const float* out_w    = (const float*)d_in[9];
    const float* ln_w     = (const float*)d_in[10];
    const float* ln_b     = (const float*)d_in[11];
    float* out = (float*)d_out;

    // ---- Workspace layout (peak 135,790,592 B, proven footprint) ----
    // [0, 33.55M)       bufX (w:in, r:conv) -> dtb (w:dt, r:scan) -> mpart[0,1]
    // [33.55M, 67.11M)  bufZ (w:in, r:scanC) -> mpart[2,3]
    // [67.11M, 83.89M)  Xh fp16 [4096][2048] (w:conv; y after scanC; r:gemms)
    // [83.89M, 92.27M)  Xe fp16 (w:1, r:2) -> Wx/dA/Wd (4-5) -> Wo (7)
    // [92.27M, 100.66M) Wi fp16 (w:1, r:2)
    // [100.66M, 102.24M) xdbl f32 [4096][96]
    // [102.24M, 135.79M) xpart [16][4096][96] (4) -> Psum@102.24M,
    //                    Hsum@119.01M (scan; ends exactly 135,790,592)
    char* ws = (char*)d_ws;
    float*    bufX  = (float*)ws;
    float*    dtb   = (float*)ws;
    float*    mpart = (float*)ws;                        // [4][4096][1024]
    float*    bufZ  = (float*)(ws + 33554432);
    _Float16* Xh    = (_Float16*)(ws + 67108864);
    _Float16* Xe    = (_Float16*)(ws + 83886080);
    _Float16* Wx    = (_Float16*)(ws + 83886080);        // [128][2048]
    _Float16* dA    = (_Float16*)(ws + 84410368);        // [4096][64]
    _Float16* Wd    = (_Float16*)(ws + 84934656);        // [2048][64]
    _Float16* Wo    = (_Float16*)(ws + 85196800);        // [1024][2048]
    _Float16* Wi    = (_Float16*)(ws + 92274688);
    float*    xdbl  = (float*)(ws + 100663296);
    float*    xpart = (float*)(ws + 102236160);          // [16][4096][96]
    float*    Psum  = (float*)(ws + 102236160);          // 16.78M (scan)
    float*    Hsum  = (float*)(ws + 119013376);          // 16.78M (scan)

    const int M = NB * LQ;  // 4096

    // 1. convert x, in_w to fp16
    cvt_h<<<M * DM / 1024, 256, 0, stream>>>(x, Xe);
    cvt_h<<<(2 * DI) * DM / 1024, 256, 0, stream>>>(in_w, Wi);

    // 2. in_proj fp16 MFMA (K=1024), epilogue deinterleaves x|z
    gemm_h<1><<<dim3((2*DI)/128, M/128), 256, 0, stream>>>(
        (const unsigned short*)Xe, (const unsigned short*)Wi,
        bufX, bufZ, nullptr, DM, 16, 0);

    // 3. conv + silu -> x fp16 (Xe/Wi dead)
    conv_silu_h<<<(M * DI) / 256, 256, 0, stream>>>(bufX, conv_w, conv_b, Xh);

    // 4. x_proj fp16 MFMA, N pad 96->128, split-K=16 (bufX dead)
    cvt_h_pad<<<dim3(DI/1024, 128), 256, 0, stream>>>(xproj_w, Wx, DI, XD);
    gemm_h<2><<<dim3(1, M/128, 16), 256, 0, stream>>>(
        (const unsigned short*)Xh, (const unsigned short*)Wx,
        xpart, nullptr, nullptr, DI, 2, 0);
    reduce16<<<(M * XD) / 256, 256, 0, stream>>>(xpart, xdbl);

    // 5. dt_proj fp16 MFMA (K=64) + softplus + bias
    cvt_h_dtA<<<(M * RK) / 256, 256, 0, stream>>>(xdbl, dA);
    cvt_h<<<DI * RK / 1024, 256, 0, stream>>>(dtproj_w, Wd);
    gemm_h<3><<<dim3(DI/128, M/128), 256, 0, stream>>>(
        (const unsigned short*)dA, (const unsigned short*)Wd,
        dtb, nullptr, dtproj_b, RK, 1, 0);

    // 6. chunked SSM scan; y overwrites Xh in place
    scan_phase_a<<<NB*CCH*8, 256, 0, stream>>>(dtb, xdbl, Xh, A_log, Psum, Hsum);
    scan_phase_b<<<(NB*DI*NS)/256, 256, 0, stream>>>(Psum, Hsum);
    scan_phase_c<<<NB*CCH*8, 256, 0, stream>>>(dtb, xdbl, Xh, bufZ, A_log, Dp, Hsum);

    // 7. out_proj fp16 MFMA, split-K=4 (dtb/bufZ/Psum/Hsum dead)
    cvt_h<<<DM * DI / 1024, 256, 0, stream>>>(out_w, Wo);
    gemm_h<4><<<dim3(DM/128, M/128, 4), 256, 0, stream>>>(
        (const unsigned short*)Xh, (const unsigned short*)Wo,
        mpart, nullptr, nullptr, DI, 8, DM);

    // 8. out = x + LayerNorm(sum of 4 partials)
    ln_res4<<<M, 256, 0, stream>>>(x, mpart, ln_w, ln_b, out);
}